// Round 4
// baseline (507.154 us; speedup 1.0000x reference)
//
#include <hip/hip_runtime.h>
#include <hip/hip_bf16.h>

typedef __attribute__((ext_vector_type(8))) short bf16x8;
typedef __attribute__((ext_vector_type(4))) float f32x4;

__device__ __forceinline__ float bfu(unsigned short u){
  union{ unsigned int i; float f; } c; c.i = ((unsigned)u) << 16; return c.f;
}
__device__ __forceinline__ float bflo(unsigned u){
  union{ unsigned int i; float f; } c; c.i = u << 16; return c.f;
}
__device__ __forceinline__ float bfhi(unsigned u){
  union{ unsigned int i; float f; } c; c.i = u & 0xffff0000u; return c.f;
}
__device__ __forceinline__ float ldval(const void* p, int i, int f32){
  return f32 ? ((const float*)p)[i] : bfu(((const unsigned short*)p)[i]);
}
__device__ __forceinline__ bf16x8 packbf8(float4 u, float4 v){
  union { bf16x8 v8; __hip_bfloat16 h[8]; } r;
  r.h[0]=__float2bfloat16(u.x); r.h[1]=__float2bfloat16(u.y);
  r.h[2]=__float2bfloat16(u.z); r.h[3]=__float2bfloat16(u.w);
  r.h[4]=__float2bfloat16(v.x); r.h[5]=__float2bfloat16(v.y);
  r.h[6]=__float2bfloat16(v.z); r.h[7]=__float2bfloat16(v.w);
  return r.v8;
}
__device__ __forceinline__ float lrelu(float v){ return v > 0.f ? v : 0.2f*v; }

// ---- dtype detect: fp32 data read as bf16 has wild exponents
__global__ void detect(const unsigned short* __restrict__ xh, int* __restrict__ flag){
  int i = blockIdx.x*256 + threadIdx.x;
  float v = fabsf(bfu(xh[i]));
  if (v > 1e4f) atomicOr(flag, 1);
}

// ---- canonicalize weights: Bt1[256][128] = [W1 | resW]^T, W2t[64][128] = W2^T, smalls fp32
__global__ void prep(const void* W1, const void* resW, const void* W2,
                     const void* a1s, const void* a1d, const void* b1,
                     const void* g, const void* bt,
                     const void* a2s, const void* a2d, const void* b2,
                     __hip_bfloat16* __restrict__ Bt1, __hip_bfloat16* __restrict__ W2t,
                     float* att1s, float* att1d, float* bias1f, float* gf, float* bfta,
                     float* att2s, float* att2d, float* bias2f, const int* flag){
  int f = *flag;
  int idx = blockIdx.x*256 + threadIdx.x;
  if (idx < 16384){ int c=idx>>7, k=idx&127; Bt1[idx] = __float2bfloat16(ldval(W1,  k*128+c, f)); }
  else if (idx < 32768){ int i=idx-16384, c=i>>7, k=i&127; Bt1[idx] = __float2bfloat16(ldval(resW,k*128+c, f)); }
  else if (idx < 40960){ int i=idx-32768, c=i>>7, k=i&127; W2t[i]  = __float2bfloat16(ldval(W2,  k*64+c,  f)); }
  else if (idx < 41088) att1s [idx-40960] = ldval(a1s, idx-40960, f);
  else if (idx < 41216) att1d [idx-41088] = ldval(a1d, idx-41088, f);
  else if (idx < 41344) bias1f[idx-41216] = ldval(b1,  idx-41216, f);
  else if (idx < 41472) gf    [idx-41344] = ldval(g,   idx-41344, f);
  else if (idx < 41600) bfta  [idx-41472] = ldval(bt,  idx-41472, f);
  else if (idx < 41664) att2s [idx-41600] = ldval(a2s, idx-41600, f);
  else if (idx < 41728) att2d [idx-41664] = ldval(a2d, idx-41664, f);
  else if (idx < 41792) bias2f[idx-41728] = ldval(b2,  idx-41728, f);
}

// ---- GEMM1: [h1 | xres] = x[N,128] @ [W1|resW]; h1->ws bf16, xres->d_out scratch bf16
__global__ __launch_bounds__(256) void gemm1(const void* __restrict__ xp,
                  const __hip_bfloat16* __restrict__ Bt1,
                  __hip_bfloat16* __restrict__ h1b,
                  __hip_bfloat16* __restrict__ xrB,
                  __hip_bfloat16* __restrict__ xrF,
                  const int* __restrict__ flag, int nn){
  int f32 = *flag;
  __hip_bfloat16* xr = f32 ? xrF : xrB;
  int wave = threadIdx.x >> 6, lane = threadIdx.x & 63;
  int m = lane & 15, q = lane >> 4;
  int n0 = blockIdx.x * 16;
  int row = n0 + m; if (row >= nn) row = nn - 1;
  f32x4 acc[4];
  #pragma unroll
  for (int ct=0; ct<4; ++ct) acc[ct] = (f32x4){0.f,0.f,0.f,0.f};
  #pragma unroll
  for (int kk=0; kk<4; ++kk){
    bf16x8 a;
    if (!f32) a = *(const bf16x8*)((const __hip_bfloat16*)xp + (size_t)row*128 + kk*32 + q*8);
    else { const float4* fp = (const float4*)((const float*)xp + (size_t)row*128 + kk*32 + q*8);
           a = packbf8(fp[0], fp[1]); }
    #pragma unroll
    for (int ct=0; ct<4; ++ct){
      int c = wave*64 + ct*16 + m;
      bf16x8 b = *(const bf16x8*)(Bt1 + (size_t)c*128 + kk*32 + q*8);
      acc[ct] = __builtin_amdgcn_mfma_f32_16x16x32_bf16(a, b, acc[ct], 0, 0, 0);
    }
  }
  #pragma unroll
  for (int ct=0; ct<4; ++ct){
    int c = wave*64 + ct*16 + m;
    #pragma unroll
    for (int i=0;i<4;++i){
      int r = n0 + q*4 + i;
      if (r < nn){
        float v = acc[ct][i];
        if (c < 128) h1b[(size_t)r*128 + c] = __float2bfloat16(v);
        else         xr [(size_t)r*128 + (c-128)] = __float2bfloat16(v);
      }
    }
  }
}

// ---- GEMM2: h2b[N,64] = bf16( h @ W2 ), h read from d_out
__global__ __launch_bounds__(256) void gemm2(const void* __restrict__ hp,
                  const __hip_bfloat16* __restrict__ W2t,
                  __hip_bfloat16* __restrict__ h2b, const int* __restrict__ flag, int nn){
  int f32 = *flag;
  int wave = threadIdx.x >> 6, lane = threadIdx.x & 63;
  int m = lane & 15, q = lane >> 4;
  int n0 = blockIdx.x * 16;
  int row = n0 + m; if (row >= nn) row = nn - 1;
  f32x4 acc = (f32x4){0.f,0.f,0.f,0.f};
  #pragma unroll
  for (int kk=0; kk<4; ++kk){
    bf16x8 a;
    if (!f32) a = *(const bf16x8*)((const __hip_bfloat16*)hp + (size_t)row*128 + kk*32 + q*8);
    else { const float4* fp = (const float4*)((const float*)hp + (size_t)row*128 + kk*32 + q*8);
           a = packbf8(fp[0], fp[1]); }
    int c = wave*16 + m;
    bf16x8 b = *(const bf16x8*)(W2t + (size_t)c*128 + kk*32 + q*8);
    acc = __builtin_amdgcn_mfma_f32_16x16x32_bf16(a, b, acc, 0, 0, 0);
  }
  int c = wave*16 + m;
  #pragma unroll
  for (int i=0;i<4;++i){
    int r = n0 + q*4 + i;
    if (r < nn) h2b[(size_t)r*64 + c] = __float2bfloat16(acc[i]);
  }
}

// ---- attention dots
__global__ void attdot1(const __hip_bfloat16* __restrict__ h1b,
                        const float* __restrict__ att1s, const float* __restrict__ att1d,
                        float* __restrict__ as1, float* __restrict__ ad1, int nn){
  int gid = blockIdx.x*256 + threadIdx.x;
  if (gid >= nn*8) return;
  int node = gid >> 3, h = gid & 7;
  const bf16x8* hp = (const bf16x8*)(h1b + (size_t)node*128 + h*16);
  bf16x8 v0 = hp[0], v1 = hp[1];
  float s=0.f, d=0.f;
  #pragma unroll
  for (int j=0;j<8;++j){
    float a = bfu((unsigned short)v0[j]);
    s += a*att1s[h*16+j]; d += a*att1d[h*16+j];
  }
  #pragma unroll
  for (int j=0;j<8;++j){
    float a = bfu((unsigned short)v1[j]);
    s += a*att1s[h*16+8+j]; d += a*att1d[h*16+8+j];
  }
  as1[gid]=s; ad1[gid]=d;
}

__global__ void attdot2(const __hip_bfloat16* __restrict__ h2b,
                        const float* __restrict__ att2s, const float* __restrict__ att2d,
                        float* __restrict__ as2, float* __restrict__ ad2, int nn){
  int gid = blockIdx.x*256 + threadIdx.x;
  if (gid >= nn) return;
  const bf16x8* hp = (const bf16x8*)(h2b + (size_t)gid*64);
  float s=0.f, d=0.f;
  #pragma unroll
  for (int t=0;t<8;++t){
    bf16x8 v = hp[t];
    #pragma unroll
    for (int j=0;j<8;++j){
      float a = bfu((unsigned short)v[j]);
      s += a*att2s[t*8+j]; d += a*att2d[t*8+j];
    }
  }
  as2[gid]=s; ad2[gid]=d;
}

// ---- CSR build
// count pass optionally ALSO records each edge's within-destination slot
// (atomicAdd return), so the fill pass needs no atomics at all.
__global__ void count_edges(const int* __restrict__ ei, int* __restrict__ cnt,
                            int* __restrict__ eoff, int E, int nn){
  int e = blockIdx.x*256 + threadIdx.x;
  if (e < E){
    int d = ei[E+e];
    int off = 0;
    if ((unsigned)d < (unsigned)nn) off = atomicAdd(&cnt[d], 1);
    if (eoff) eoff[e] = off;           // coalesced 4B write
  }
}

__global__ void scan_part(const int* __restrict__ cnt, int* __restrict__ part, int n){
  __shared__ int red[256];
  int t = threadIdx.x;
  int base = blockIdx.x*1024 + t*4;
  int s = 0;
  #pragma unroll
  for (int j=0;j<4;++j){ int i = base + j; if (i < n) s += cnt[i]; }
  red[t] = s; __syncthreads();
  for (int off=128; off>0; off>>=1){
    if (t < off) red[t] += red[t+off];
    __syncthreads();
  }
  if (t == 0) part[blockIdx.x] = red[0];
}

__global__ void scan_mid(int* __restrict__ part, int nb, int* __restrict__ row_ptr, int n){
  __shared__ int sd[256];
  int t = threadIdx.x;
  int v = (t < nb) ? part[t] : 0;
  sd[t] = v; __syncthreads();
  for (int off=1; off<256; off<<=1){
    int xv = (t >= off) ? sd[t-off] : 0;
    __syncthreads();
    sd[t] += xv;
    __syncthreads();
  }
  if (t < nb) part[t] = sd[t] - v;
  if (t == 0) row_ptr[n] = sd[255];
}

__global__ void scan_write(const int* __restrict__ cnt, const int* __restrict__ part,
                           int* __restrict__ row_ptr, int n){
  __shared__ int sd[256];
  int t = threadIdx.x;
  int base = blockIdx.x*1024 + t*4;
  int v0=0,v1=0,v2=0,v3=0;
  if (base   < n) v0 = cnt[base];
  if (base+1 < n) v1 = cnt[base+1];
  if (base+2 < n) v2 = cnt[base+2];
  if (base+3 < n) v3 = cnt[base+3];
  int s = v0+v1+v2+v3;
  sd[t] = s; __syncthreads();
  for (int off=1; off<256; off<<=1){
    int xv = (t >= off) ? sd[t-off] : 0;
    __syncthreads();
    sd[t] += xv;
    __syncthreads();
  }
  int run = part[blockIdx.x] + sd[t] - s;
  if (base   < n) row_ptr[base]   = run; run += v0;
  if (base+1 < n) row_ptr[base+1] = run; run += v1;
  if (base+2 < n) row_ptr[base+2] = run; run += v2;
  if (base+3 < n) row_ptr[base+3] = run;
}

// atomic-free fill: pos = rowp[dst] + eoff[e]; pure scatter store, full MLP
__global__ void fill_csr(const int* __restrict__ ei, const int* __restrict__ row_ptr,
                         const int* __restrict__ eoff, int* __restrict__ csr,
                         int E, int nn){
  int e = blockIdx.x*256 + threadIdx.x;
  if (e < E){
    int d = ei[E+e];
    if ((unsigned)d < (unsigned)nn){
      int pos = row_ptr[d] + eoff[e];
      if ((unsigned)pos < (unsigned)E) csr[pos] = ei[e];
    }
  }
}

// fallback (tiny-workspace case): original atomic fill
__global__ void fill_csr_atomic(const int* __restrict__ ei, const int* __restrict__ row_ptr,
                                int* __restrict__ cur, int* __restrict__ csr, int E, int nn){
  int e = blockIdx.x*256 + threadIdx.x;
  if (e < E){
    int d = ei[E+e];
    if ((unsigned)d < (unsigned)nn){
      int pos = row_ptr[d] + atomicAdd(&cur[d], 1);
      if ((unsigned)pos < (unsigned)E) csr[pos] = ei[e];
    }
  }
}

// ---- layer-1 aggregate + xres + LayerNorm + ELU; 1 wave/node
// 16B/lane gathers, 4 groups of 16 lanes; 4-edge-granular uniform tail guards
// (Poisson(16) degrees: fixed 16-slot chunks waste ~32% of slots; guards cut
// that to ~6%). Partial sub-batches stay correct via the weight mask (w=0).
__global__ __launch_bounds__(256) void agg1(
    const __hip_bfloat16* __restrict__ h1b,
    const float* __restrict__ as1, const float* __restrict__ ad1,
    const int* __restrict__ rowp, const int* __restrict__ csr,
    const __hip_bfloat16* __restrict__ xrB, const __hip_bfloat16* __restrict__ xrF,
    const float* __restrict__ bias1f, const float* __restrict__ gf,
    const float* __restrict__ bfta,
    const int* __restrict__ flag, void* __restrict__ dout, int nn, int Etot){
  int f32 = *flag;
  int w = threadIdx.x >> 6, lane = threadIdx.x & 63;
  int n = blockIdx.x*4 + w;
  if (n >= nn) return;
  int g = lane >> 4, t = lane & 15;    // group, position-in-row
  int c0 = t*8;                        // my 8 channels
  int h = t >> 1;                      // my head (channels c0..c0+7 lie in head t/2)
  int wh = lane & 7;                   // weight role: head wh, edges b+(lane>>3), +8
  const __hip_bfloat16* xr = f32 ? xrF : xrB;
  float adc = ad1[n*8 + h];
  float adw = ad1[n*8 + wh];
  float asn = as1[n*8 + h];
  bf16x8 hs = *(const bf16x8*)(h1b + (size_t)n*128 + c0);   // self row, 16B/lane
  int p0 = rowp[n], pe = rowp[n+1];
  if (p0 < 0) p0 = 0; if (pe > Etot) pe = Etot;
  int p0u = __builtin_amdgcn_readfirstlane(p0);
  int peu = __builtin_amdgcn_readfirstlane(pe);
  float selfw = __expf(fminf(lrelu(asn + adc), 30.f));
  float sw0 = (g == 0) ? selfw : 0.f;  // count self-loop in exactly one group
  float acc[8];
  { union { bf16x8 v; uint4 u; } cv; cv.v = hs;
    acc[0]=sw0*bflo(cv.u.x); acc[1]=sw0*bfhi(cv.u.x);
    acc[2]=sw0*bflo(cv.u.y); acc[3]=sw0*bfhi(cv.u.y);
    acc[4]=sw0*bflo(cv.u.z); acc[5]=sw0*bfhi(cv.u.z);
    acc[6]=sw0*bflo(cv.u.w); acc[7]=sw0*bfhi(cv.u.w); }
  float denp = 0.f;
  int idxA = g*8 + h;                  // weight lane for edge-offset g   (w0) / 8+g (w1)
  int idxB = idxA + 32;                // weight lane for edge-offset 4+g (w0) / 12+g (w1)
  for (int b = p0u; b < peu; b += 16){
    // weight lanes: edges b+(lane>>3) and b+8+(lane>>3), head wh
    int e0i = b + (lane>>3);
    int e1i = e0i + 8;
    int j0 = e0i < peu ? e0i : peu-1;
    int j1 = e1i < peu ? e1i : peu-1;
    int s0 = csr[j0]; if ((unsigned)s0 >= (unsigned)nn) s0 = 0;
    int s1 = csr[j1]; if ((unsigned)s1 >= (unsigned)nn) s1 = 0;
    float av0 = as1[(size_t)s0*8 + wh];
    float av1 = as1[(size_t)s1*8 + wh];
    float w0 = __expf(fminf(lrelu(av0 + adw), 30.f)) * (e0i < peu ? 1.f : 0.f);
    float w1 = __expf(fminf(lrelu(av1 + adw), 30.f)) * (e1i < peu ? 1.f : 0.f);
    denp += w0 + w1;
    int nb = peu - b;                  // uniform: live slots this chunk
    // batch present 4-edge sub-batches (edges b+4i+g) to keep MLP
    bf16x8 hv[4]; float wb[4];
    #pragma unroll
    for (int i=0;i<4;++i){
      if (4*i < nb){
        int sv = __shfl(i < 2 ? s0 : s1, (i & 1) ? idxB : idxA);
        wb[i]  = __shfl(i < 2 ? w0 : w1, (i & 1) ? idxB : idxA);
        hv[i] = *(const bf16x8*)(h1b + (size_t)sv*128 + c0);
      }
    }
    #pragma unroll
    for (int i=0;i<4;++i){
      if (4*i < nb){
        union { bf16x8 v; uint4 u; } cv; cv.v = hv[i];
        float wv = wb[i];
        acc[0] += wv*bflo(cv.u.x); acc[1] += wv*bfhi(cv.u.x);
        acc[2] += wv*bflo(cv.u.y); acc[3] += wv*bfhi(cv.u.y);
        acc[4] += wv*bflo(cv.u.z); acc[5] += wv*bfhi(cv.u.z);
        acc[6] += wv*bflo(cv.u.w); acc[7] += wv*bfhi(cv.u.w);
      }
    }
  }
  // reduce the 4 redundant group accumulators (all lanes end up with full sums)
  #pragma unroll
  for (int j=0;j<8;++j){
    acc[j] += __shfl_xor(acc[j], 16);
    acc[j] += __shfl_xor(acc[j], 32);
  }
  // denom: sum lanes with same wh (bits 3..5), then fetch my head's total
  denp += __shfl_xor(denp, 8);
  denp += __shfl_xor(denp, 16);
  denp += __shfl_xor(denp, 32);
  float den = __shfl(denp, h) + selfw;
  float inv = 1.f/(den + 1e-16f);
  // residual + bias + LayerNorm + ELU
  bf16x8 xv = *(const bf16x8*)(xr + (size_t)n*128 + c0);
  union { bf16x8 v; uint4 u; } xc; xc.v = xv;
  float xf[8] = { bflo(xc.u.x), bfhi(xc.u.x), bflo(xc.u.y), bfhi(xc.u.y),
                  bflo(xc.u.z), bfhi(xc.u.z), bflo(xc.u.w), bfhi(xc.u.w) };
  float4 bA = *(const float4*)(bias1f + c0), bB = *(const float4*)(bias1f + c0 + 4);
  float bb[8] = { bA.x,bA.y,bA.z,bA.w, bB.x,bB.y,bB.z,bB.w };
  float o[8];
  float s1 = 0.f, s2 = 0.f;
  #pragma unroll
  for (int j=0;j<8;++j){
    o[j] = acc[j]*inv + xf[j] + bb[j];
    s1 += o[j]; s2 += o[j]*o[j];
  }
  // groups hold identical values -> reduce over t bits (0..3) only
  #pragma unroll
  for (int off=1; off<16; off<<=1){
    s1 += __shfl_xor(s1, off);
    s2 += __shfl_xor(s2, off);
  }
  float mu  = s1 * (1.f/128.f);
  float var = s2 * (1.f/128.f) - mu*mu;
  float rstd = rsqrtf(var + 1e-5f);
  float4 gA = *(const float4*)(gf + c0),   gB = *(const float4*)(gf + c0 + 4);
  float4 tA = *(const float4*)(bfta + c0), tB = *(const float4*)(bfta + c0 + 4);
  float gg[8] = { gA.x,gA.y,gA.z,gA.w, gB.x,gB.y,gB.z,gB.w };
  float tt[8] = { tA.x,tA.y,tA.z,tA.w, tB.x,tB.y,tB.z,tB.w };
  #pragma unroll
  for (int j=0;j<8;++j){
    float v = (o[j]-mu)*rstd*gg[j] + tt[j];
    o[j] = v > 0.f ? v : __expf(v) - 1.f;
  }
  if (g == 0){
    if (!f32){
      bf16x8 ov = packbf8((float4){o[0],o[1],o[2],o[3]}, (float4){o[4],o[5],o[6],o[7]});
      *(bf16x8*)((__hip_bfloat16*)dout + (size_t)n*128 + c0) = ov;
    } else {
      float* op = (float*)dout + (size_t)n*128 + c0;
      *(float4*)op     = (float4){o[0],o[1],o[2],o[3]};
      *(float4*)(op+4) = (float4){o[4],o[5],o[6],o[7]};
    }
  }
}

// ---- layer-2 aggregate; 1 wave/node. 16B/lane gathers, 8 groups of 8 lanes.
// 8-edge-granular uniform guards (was 32): deg=16 node now touches 16 slots, not 32.
__global__ __launch_bounds__(256) void agg2(const __hip_bfloat16* __restrict__ h2b,
    const float* __restrict__ as2, const float* __restrict__ ad2,
    const int* __restrict__ rowp, const int* __restrict__ csr,
    const float* __restrict__ bias2f,
    const int* __restrict__ flag, void* __restrict__ dout, int nn, int Etot){
  int f32 = *flag;
  int w = threadIdx.x >> 6, lane = threadIdx.x & 63;
  int n = blockIdx.x*4 + w;
  if (n >= nn) return;
  int g = lane >> 3, t = lane & 7;     // group, position-in-row
  int c0 = t*8;                        // my 8 channels
  float adst = ad2[n];
  float selfw = __expf(fminf(lrelu(as2[n] + adst), 30.f));
  float sw0 = (g == 0) ? selfw : 0.f;
  bf16x8 hs = *(const bf16x8*)(h2b + (size_t)n*64 + c0);
  float acc[8];
  { union { bf16x8 v; uint4 u; } cv; cv.v = hs;
    acc[0]=sw0*bflo(cv.u.x); acc[1]=sw0*bfhi(cv.u.x);
    acc[2]=sw0*bflo(cv.u.y); acc[3]=sw0*bfhi(cv.u.y);
    acc[4]=sw0*bflo(cv.u.z); acc[5]=sw0*bfhi(cv.u.z);
    acc[6]=sw0*bflo(cv.u.w); acc[7]=sw0*bfhi(cv.u.w); }
  float denp = 0.f;
  int p0 = rowp[n], pe = rowp[n+1];
  if (p0 < 0) p0 = 0; if (pe > Etot) pe = Etot;
  int p0u = __builtin_amdgcn_readfirstlane(p0);
  int peu = __builtin_amdgcn_readfirstlane(pe);
  for (int b = p0u; b < peu; b += 64){
    // weight lanes: edge b+lane
    int ei = b + lane;
    int ji = ei < peu ? ei : peu-1;
    int si = csr[ji]; if ((unsigned)si >= (unsigned)nn) si = 0;
    float av = as2[si];
    float wv = __expf(fminf(lrelu(av + adst), 30.f)) * (ei < peu ? 1.f : 0.f);
    denp += wv;
    int nb = peu - b;                  // uniform: live slots this chunk
    #pragma unroll
    for (int ib = 0; ib < 8; ib += 4){
      if (8*ib < nb){
        bf16x8 hv[4]; float wb[4];
        #pragma unroll
        for (int u=0;u<4;++u){
          int i = ib + u;
          if (8*i < nb){               // uniform, 8-edge granularity
            int sv = __shfl(si, g + 8*i);
            wb[u]  = __shfl(wv, g + 8*i);
            hv[u] = *(const bf16x8*)(h2b + (size_t)sv*64 + c0);
          }
        }
        #pragma unroll
        for (int u=0;u<4;++u){
          int i = ib + u;
          if (8*i < nb){
            union { bf16x8 v; uint4 uu; } cv; cv.v = hv[u];
            float wx = wb[u];
            acc[0] += wx*bflo(cv.uu.x); acc[1] += wx*bfhi(cv.uu.x);
            acc[2] += wx*bflo(cv.uu.y); acc[3] += wx*bfhi(cv.uu.y);
            acc[4] += wx*bflo(cv.uu.z); acc[5] += wx*bfhi(cv.uu.z);
            acc[6] += wx*bflo(cv.uu.w); acc[7] += wx*bfhi(cv.uu.w);
          }
        }
      }
    }
  }
  // reduce the 8 redundant group accumulators
  #pragma unroll
  for (int j=0;j<8;++j){
    acc[j] += __shfl_xor(acc[j], 8);
    acc[j] += __shfl_xor(acc[j], 16);
    acc[j] += __shfl_xor(acc[j], 32);
  }
  denp += __shfl_xor(denp, 1);
  denp += __shfl_xor(denp, 2);
  denp += __shfl_xor(denp, 4);
  denp += __shfl_xor(denp, 8);
  denp += __shfl_xor(denp, 16);
  denp += __shfl_xor(denp, 32);
  float den = denp + selfw;
  float inv = 1.f/(den + 1e-16f);
  float4 bA = *(const float4*)(bias2f + c0), bB = *(const float4*)(bias2f + c0 + 4);
  float bb[8] = { bA.x,bA.y,bA.z,bA.w, bB.x,bB.y,bB.z,bB.w };
  float o[8];
  #pragma unroll
  for (int j=0;j<8;++j) o[j] = acc[j]*inv + bb[j];
  if (g == 0){
    if (!f32){
      bf16x8 ov = packbf8((float4){o[0],o[1],o[2],o[3]}, (float4){o[4],o[5],o[6],o[7]});
      *(bf16x8*)((__hip_bfloat16*)dout + (size_t)nn*128 + (size_t)n*64 + c0) = ov;
    } else {
      float* op = (float*)dout + (size_t)nn*128 + (size_t)n*64 + c0;
      *(float4*)op     = (float4){o[0],o[1],o[2],o[3]};
      *(float4*)(op+4) = (float4){o[4],o[5],o[6],o[7]};
    }
  }
}

extern "C" void kernel_launch(void* const* d_in, const int* in_sizes, int n_in,
                              void* d_out, int out_size, void* d_ws, size_t ws_size,
                              hipStream_t stream){
  (void)n_in; (void)out_size;
  const void* x     = d_in[0];
  const int*  ei    = (const int*)d_in[1];
  const void* W1    = d_in[2];
  const void* a1s   = d_in[3];
  const void* a1d   = d_in[4];
  const void* b1    = d_in[5];
  const void* resW  = d_in[6];
  const void* g     = d_in[7];
  const void* bt    = d_in[8];
  const void* W2    = d_in[9];
  const void* a2s   = d_in[10];
  const void* a2d   = d_in[11];
  const void* b2    = d_in[12];

  int N = in_sizes[0] / 128;
  int E = in_sizes[1] / 2;

  __hip_bfloat16* xrB = (__hip_bfloat16*)d_out;
  __hip_bfloat16* xrF = (__hip_bfloat16*)((float*)d_out + (size_t)N*128);

  char* ws = (char*)d_ws;
  size_t o = 0;
  auto alloc = [&](size_t bytes)->char*{ char* r = ws + o; o = (o + bytes + 255) & ~(size_t)255; return r; };
  int*   flag = (int*)  alloc(4);
  int*   part = (int*)  alloc(4096);
  int*   rowp = (int*)  alloc(((size_t)N+1)*4);
  int*   cnt  = (int*)  alloc((size_t)N*4);
  float* as1  = (float*)alloc((size_t)N*8*4);
  float* ad1  = (float*)alloc((size_t)N*8*4);
  int*   csr  = (int*)  alloc((size_t)E*4);
  __hip_bfloat16* h1b = (__hip_bfloat16*)alloc((size_t)N*128*2);
  __hip_bfloat16* Bt1 = (__hip_bfloat16*)alloc(65536);
  __hip_bfloat16* W2t = (__hip_bfloat16*)alloc(16384);
  float* att1s  = (float*)alloc(512);
  float* att1d  = (float*)alloc(512);
  float* bias1f = (float*)alloc(512);
  float* gfv    = (float*)alloc(512);
  float* bfv    = (float*)alloc(512);
  float* att2s  = (float*)alloc(256);
  float* att2d  = (float*)alloc(256);
  float* bias2f = (float*)alloc(256);
  // eoff LAST: if workspace can't fit it, fall back to the atomic fill path
  int*   eoff = (int*)  alloc((size_t)E*4);
  int use_eoff = (o <= ws_size);
  __hip_bfloat16* h2b = h1b;
  float* as2 = as1;
  float* ad2 = ad1;

  int EB = (E + 255)/256;
  int NB = (N + 1023)/1024;

  (void)hipMemsetAsync(flag, 0, 4, stream);
  (void)hipMemsetAsync(cnt,  0, (size_t)N*4, stream);
  detect<<<16, 256, 0, stream>>>((const unsigned short*)x, flag);
  prep<<<164, 256, 0, stream>>>(W1, resW, W2, a1s, a1d, b1, g, bt, a2s, a2d, b2,
                                Bt1, W2t, att1s, att1d, bias1f, gfv, bfv,
                                att2s, att2d, bias2f, flag);
  gemm1<<<(N+15)/16, 256, 0, stream>>>(x, Bt1, h1b, xrB, xrF, flag, N);
  count_edges<<<EB, 256, 0, stream>>>(ei, cnt, use_eoff ? eoff : (int*)nullptr, E, N);
  scan_part<<<NB, 256, 0, stream>>>(cnt, part, N);
  scan_mid<<<1, 256, 0, stream>>>(part, NB, rowp, N);
  scan_write<<<NB, 256, 0, stream>>>(cnt, part, rowp, N);
  if (use_eoff){
    fill_csr<<<EB, 256, 0, stream>>>(ei, rowp, eoff, csr, E, N);
  } else {
    (void)hipMemsetAsync(cnt, 0, (size_t)N*4, stream);
    fill_csr_atomic<<<EB, 256, 0, stream>>>(ei, rowp, cnt, csr, E, N);
  }
  attdot1<<<(N*8 + 255)/256, 256, 0, stream>>>(h1b, att1s, att1d, as1, ad1, N);
  agg1<<<(N+3)/4, 256, 0, stream>>>(h1b, as1, ad1, rowp, csr, xrB, xrF,
                                    bias1f, gfv, bfv, flag, d_out, N, E);
  gemm2<<<(N+15)/16, 256, 0, stream>>>(d_out, W2t, h2b, flag, N);
  attdot2<<<(N+255)/256, 256, 0, stream>>>(h2b, att2s, att2d, as2, ad2, N);
  agg2<<<(N+3)/4, 256, 0, stream>>>(h2b, as2, ad2, rowp, csr, bias2f, flag, d_out, N, E);
}

// Round 5
// 488.786 us; speedup vs baseline: 1.0376x; 1.0376x over previous
//
#include <hip/hip_runtime.h>
#include <hip/hip_bf16.h>

typedef __attribute__((ext_vector_type(8))) short bf16x8;
typedef __attribute__((ext_vector_type(4))) float f32x4;

__device__ __forceinline__ float bfu(unsigned short u){
  union{ unsigned int i; float f; } c; c.i = ((unsigned)u) << 16; return c.f;
}
__device__ __forceinline__ float bflo(unsigned u){
  union{ unsigned int i; float f; } c; c.i = u << 16; return c.f;
}
__device__ __forceinline__ float bfhi(unsigned u){
  union{ unsigned int i; float f; } c; c.i = u & 0xffff0000u; return c.f;
}
__device__ __forceinline__ float ldval(const void* p, int i, int f32){
  return f32 ? ((const float*)p)[i] : bfu(((const unsigned short*)p)[i]);
}
__device__ __forceinline__ bf16x8 packbf8(float4 u, float4 v){
  union { bf16x8 v8; __hip_bfloat16 h[8]; } r;
  r.h[0]=__float2bfloat16(u.x); r.h[1]=__float2bfloat16(u.y);
  r.h[2]=__float2bfloat16(u.z); r.h[3]=__float2bfloat16(u.w);
  r.h[4]=__float2bfloat16(v.x); r.h[5]=__float2bfloat16(v.y);
  r.h[6]=__float2bfloat16(v.z); r.h[7]=__float2bfloat16(v.w);
  return r.v8;
}
__device__ __forceinline__ float lrelu(float v){ return v > 0.f ? v : 0.2f*v; }

// ---- dtype detect: fp32 data read as bf16 has wild exponents
__global__ void detect(const unsigned short* __restrict__ xh, int* __restrict__ flag){
  int i = blockIdx.x*256 + threadIdx.x;
  float v = fabsf(bfu(xh[i]));
  if (v > 1e4f) atomicOr(flag, 1);
}

// ---- canonicalize weights: Bt1[256][128] = [W1 | resW]^T, W2t[64][128] = W2^T, smalls fp32
__global__ void prep(const void* W1, const void* resW, const void* W2,
                     const void* a1s, const void* a1d, const void* b1,
                     const void* g, const void* bt,
                     const void* a2s, const void* a2d, const void* b2,
                     __hip_bfloat16* __restrict__ Bt1, __hip_bfloat16* __restrict__ W2t,
                     float* att1s, float* att1d, float* bias1f, float* gf, float* bfta,
                     float* att2s, float* att2d, float* bias2f, const int* flag){
  int f = *flag;
  int idx = blockIdx.x*256 + threadIdx.x;
  if (idx < 16384){ int c=idx>>7, k=idx&127; Bt1[idx] = __float2bfloat16(ldval(W1,  k*128+c, f)); }
  else if (idx < 32768){ int i=idx-16384, c=i>>7, k=i&127; Bt1[idx] = __float2bfloat16(ldval(resW,k*128+c, f)); }
  else if (idx < 40960){ int i=idx-32768, c=i>>7, k=i&127; W2t[i]  = __float2bfloat16(ldval(W2,  k*64+c,  f)); }
  else if (idx < 41088) att1s [idx-40960] = ldval(a1s, idx-40960, f);
  else if (idx < 41216) att1d [idx-41088] = ldval(a1d, idx-41088, f);
  else if (idx < 41344) bias1f[idx-41216] = ldval(b1,  idx-41216, f);
  else if (idx < 41472) gf    [idx-41344] = ldval(g,   idx-41344, f);
  else if (idx < 41600) bfta  [idx-41472] = ldval(bt,  idx-41472, f);
  else if (idx < 41664) att2s [idx-41600] = ldval(a2s, idx-41600, f);
  else if (idx < 41728) att2d [idx-41664] = ldval(a2d, idx-41664, f);
  else if (idx < 41792) bias2f[idx-41728] = ldval(b2,  idx-41728, f);
}

// ---- FAT kernel: blocks [0,G) do GEMM1 (+fused attdot1 epilogue);
//      blocks [G, G+EB) do count_edges (independent atomic histogram).
// The atomic-latency-bound histogram co-resides with the MFMA/BW-bound GEMM.
__global__ __launch_bounds__(256) void gemm1_fat(const void* __restrict__ xp,
                  const __hip_bfloat16* __restrict__ Bt1,
                  __hip_bfloat16* __restrict__ h1b,
                  __hip_bfloat16* __restrict__ xrB,
                  __hip_bfloat16* __restrict__ xrF,
                  const float* __restrict__ att1s, const float* __restrict__ att1d,
                  float* __restrict__ as1, float* __restrict__ ad1,
                  const int* __restrict__ ei, int* __restrict__ cnt,
                  int* __restrict__ eoff,
                  const int* __restrict__ flag, int nn, int E, int G){
  __shared__ __hip_bfloat16 sh[16][128];
  if ((int)blockIdx.x >= G){
    // ---- count_edges role (no barriers on this path; block-uniform branch)
    int e = ((int)blockIdx.x - G)*256 + threadIdx.x;
    if (e < E){
      int d = ei[E+e];
      int off = 0;
      if ((unsigned)d < (unsigned)nn) off = atomicAdd(&cnt[d], 1);
      if (eoff) eoff[e] = off;         // coalesced 4B write
    }
    return;
  }
  int f32 = *flag;
  __hip_bfloat16* xr = f32 ? xrF : xrB;
  int wave = threadIdx.x >> 6, lane = threadIdx.x & 63;
  int m = lane & 15, q = lane >> 4;
  int n0 = blockIdx.x * 16;
  int row = n0 + m; if (row >= nn) row = nn - 1;
  f32x4 acc[4];
  #pragma unroll
  for (int ct=0; ct<4; ++ct) acc[ct] = (f32x4){0.f,0.f,0.f,0.f};
  #pragma unroll
  for (int kk=0; kk<4; ++kk){
    bf16x8 a;
    if (!f32) a = *(const bf16x8*)((const __hip_bfloat16*)xp + (size_t)row*128 + kk*32 + q*8);
    else { const float4* fp = (const float4*)((const float*)xp + (size_t)row*128 + kk*32 + q*8);
           a = packbf8(fp[0], fp[1]); }
    #pragma unroll
    for (int ct=0; ct<4; ++ct){
      int c = wave*64 + ct*16 + m;
      bf16x8 b = *(const bf16x8*)(Bt1 + (size_t)c*128 + kk*32 + q*8);
      acc[ct] = __builtin_amdgcn_mfma_f32_16x16x32_bf16(a, b, acc[ct], 0, 0, 0);
    }
  }
  #pragma unroll
  for (int ct=0; ct<4; ++ct){
    int c = wave*64 + ct*16 + m;
    #pragma unroll
    for (int i=0;i<4;++i){
      int r = n0 + q*4 + i;
      if (r < nn){
        __hip_bfloat16 hv = __float2bfloat16(acc[ct][i]);
        if (c < 128){ h1b[(size_t)r*128 + c] = hv; sh[q*4+i][c] = hv; }
        else          xr [(size_t)r*128 + (c-128)] = hv;
      }
    }
  }
  __syncthreads();
  // ---- fused attdot1: threads 0..127 -> (row r, head h) dot from LDS tile
  int tid = threadIdx.x;
  if (tid < 128){
    int r = tid >> 3, h = tid & 7;
    if (n0 + r < nn){
      const bf16x8* hp = (const bf16x8*)&sh[r][h*16];
      bf16x8 v0 = hp[0], v1 = hp[1];
      float s=0.f, d=0.f;
      #pragma unroll
      for (int j=0;j<8;++j){
        float a = bfu((unsigned short)v0[j]);
        s += a*att1s[h*16+j]; d += a*att1d[h*16+j];
      }
      #pragma unroll
      for (int j=0;j<8;++j){
        float a = bfu((unsigned short)v1[j]);
        s += a*att1s[h*16+8+j]; d += a*att1d[h*16+8+j];
      }
      as1[(size_t)(n0+r)*8 + h] = s;
      ad1[(size_t)(n0+r)*8 + h] = d;
    }
  }
}

// ---- GEMM2 + fused attdot2 epilogue: h2b[N,64] = bf16( h @ W2 )
__global__ __launch_bounds__(256) void gemm2_fat(const void* __restrict__ hp,
                  const __hip_bfloat16* __restrict__ W2t,
                  __hip_bfloat16* __restrict__ h2b,
                  const float* __restrict__ att2s, const float* __restrict__ att2d,
                  float* __restrict__ as2, float* __restrict__ ad2,
                  const int* __restrict__ flag, int nn){
  __shared__ __hip_bfloat16 sh2[16][64];
  int f32 = *flag;
  int wave = threadIdx.x >> 6, lane = threadIdx.x & 63;
  int m = lane & 15, q = lane >> 4;
  int n0 = blockIdx.x * 16;
  int row = n0 + m; if (row >= nn) row = nn - 1;
  f32x4 acc = (f32x4){0.f,0.f,0.f,0.f};
  #pragma unroll
  for (int kk=0; kk<4; ++kk){
    bf16x8 a;
    if (!f32) a = *(const bf16x8*)((const __hip_bfloat16*)hp + (size_t)row*128 + kk*32 + q*8);
    else { const float4* fp = (const float4*)((const float*)hp + (size_t)row*128 + kk*32 + q*8);
           a = packbf8(fp[0], fp[1]); }
    int c = wave*16 + m;
    bf16x8 b = *(const bf16x8*)(W2t + (size_t)c*128 + kk*32 + q*8);
    acc = __builtin_amdgcn_mfma_f32_16x16x32_bf16(a, b, acc, 0, 0, 0);
  }
  int c = wave*16 + m;
  #pragma unroll
  for (int i=0;i<4;++i){
    int r = n0 + q*4 + i;
    if (r < nn){
      __hip_bfloat16 hv = __float2bfloat16(acc[i]);
      h2b[(size_t)r*64 + c] = hv;
      sh2[q*4+i][c] = hv;
    }
  }
  __syncthreads();
  // fused attdot2: thread r (0..15) dots row r against att2s/att2d
  int tid = threadIdx.x;
  if (tid < 16 && n0 + tid < nn){
    const bf16x8* rp = (const bf16x8*)&sh2[tid][0];
    float s=0.f, d=0.f;
    #pragma unroll
    for (int t=0;t<8;++t){
      bf16x8 v = rp[t];
      #pragma unroll
      for (int j=0;j<8;++j){
        float a = bfu((unsigned short)v[j]);
        s += a*att2s[t*8+j]; d += a*att2d[t*8+j];
      }
    }
    as2[n0+tid]=s; ad2[n0+tid]=d;
  }
}

__global__ void scan_part(const int* __restrict__ cnt, int* __restrict__ part, int n){
  __shared__ int red[256];
  int t = threadIdx.x;
  int base = blockIdx.x*1024 + t*4;
  int s = 0;
  #pragma unroll
  for (int j=0;j<4;++j){ int i = base + j; if (i < n) s += cnt[i]; }
  red[t] = s; __syncthreads();
  for (int off=128; off>0; off>>=1){
    if (t < off) red[t] += red[t+off];
    __syncthreads();
  }
  if (t == 0) part[blockIdx.x] = red[0];
}

__global__ void scan_mid(int* __restrict__ part, int nb, int* __restrict__ row_ptr, int n){
  __shared__ int sd[256];
  int t = threadIdx.x;
  int v = (t < nb) ? part[t] : 0;
  sd[t] = v; __syncthreads();
  for (int off=1; off<256; off<<=1){
    int xv = (t >= off) ? sd[t-off] : 0;
    __syncthreads();
    sd[t] += xv;
    __syncthreads();
  }
  if (t < nb) part[t] = sd[t] - v;
  if (t == 0) row_ptr[n] = sd[255];
}

__global__ void scan_write(const int* __restrict__ cnt, const int* __restrict__ part,
                           int* __restrict__ row_ptr, int n){
  __shared__ int sd[256];
  int t = threadIdx.x;
  int base = blockIdx.x*1024 + t*4;
  int v0=0,v1=0,v2=0,v3=0;
  if (base   < n) v0 = cnt[base];
  if (base+1 < n) v1 = cnt[base+1];
  if (base+2 < n) v2 = cnt[base+2];
  if (base+3 < n) v3 = cnt[base+3];
  int s = v0+v1+v2+v3;
  sd[t] = s; __syncthreads();
  for (int off=1; off<256; off<<=1){
    int xv = (t >= off) ? sd[t-off] : 0;
    __syncthreads();
    sd[t] += xv;
    __syncthreads();
  }
  int run = part[blockIdx.x] + sd[t] - s;
  if (base   < n) row_ptr[base]   = run; run += v0;
  if (base+1 < n) row_ptr[base+1] = run; run += v1;
  if (base+2 < n) row_ptr[base+2] = run; run += v2;
  if (base+3 < n) row_ptr[base+3] = run;
}

// atomic-free fill: pos = rowp[dst] + eoff[e]; pure scatter store, full MLP
__global__ void fill_csr(const int* __restrict__ ei, const int* __restrict__ row_ptr,
                         const int* __restrict__ eoff, int* __restrict__ csr,
                         int E, int nn){
  int e = blockIdx.x*256 + threadIdx.x;
  if (e < E){
    int d = ei[E+e];
    if ((unsigned)d < (unsigned)nn){
      int pos = row_ptr[d] + eoff[e];
      if ((unsigned)pos < (unsigned)E) csr[pos] = ei[e];
    }
  }
}

// fallback (tiny-workspace case): original atomic fill
__global__ void fill_csr_atomic(const int* __restrict__ ei, const int* __restrict__ row_ptr,
                                int* __restrict__ cur, int* __restrict__ csr, int E, int nn){
  int e = blockIdx.x*256 + threadIdx.x;
  if (e < E){
    int d = ei[E+e];
    if ((unsigned)d < (unsigned)nn){
      int pos = row_ptr[d] + atomicAdd(&cur[d], 1);
      if ((unsigned)pos < (unsigned)E) csr[pos] = ei[e];
    }
  }
}

// ---- layer-1 aggregate + xres + LayerNorm + ELU; 1 wave/node
// 16B/lane gathers. 4 groups of 16 lanes; group g loads edge (b+4i+g)'s full
// row (16 lanes x 16B = 256B); lane owns 8 fixed channels -> 4-way-redundant acc,
// reduced with shfl_xor(16,32) once per node. src id + weight bpermuted from the
// weight-role lanes (2 bpermutes per 4 edges; no per-edge csr reload).
__global__ __launch_bounds__(256) void agg1(
    const __hip_bfloat16* __restrict__ h1b,
    const float* __restrict__ as1, const float* __restrict__ ad1,
    const int* __restrict__ rowp, const int* __restrict__ csr,
    const __hip_bfloat16* __restrict__ xrB, const __hip_bfloat16* __restrict__ xrF,
    const float* __restrict__ bias1f, const float* __restrict__ gf,
    const float* __restrict__ bfta,
    const int* __restrict__ flag, void* __restrict__ dout, int nn, int Etot){
  int f32 = *flag;
  int w = threadIdx.x >> 6, lane = threadIdx.x & 63;
  int n = blockIdx.x*4 + w;
  if (n >= nn) return;
  int g = lane >> 4, t = lane & 15;    // group, position-in-row
  int c0 = t*8;                        // my 8 channels
  int h = t >> 1;                      // my head (channels c0..c0+7 lie in head t/2)
  int wh = lane & 7;                   // weight role: head wh, edges b+(lane>>3), +8
  const __hip_bfloat16* xr = f32 ? xrF : xrB;
  float adc = ad1[n*8 + h];
  float adw = ad1[n*8 + wh];
  float asn = as1[n*8 + h];
  bf16x8 hs = *(const bf16x8*)(h1b + (size_t)n*128 + c0);   // self row, 16B/lane
  int p0 = rowp[n], pe = rowp[n+1];
  if (p0 < 0) p0 = 0; if (pe > Etot) pe = Etot;
  int p0u = __builtin_amdgcn_readfirstlane(p0);
  int peu = __builtin_amdgcn_readfirstlane(pe);
  float selfw = __expf(fminf(lrelu(asn + adc), 30.f));
  float sw0 = (g == 0) ? selfw : 0.f;  // count self-loop in exactly one group
  float acc[8];
  { union { bf16x8 v; uint4 u; } cv; cv.v = hs;
    acc[0]=sw0*bflo(cv.u.x); acc[1]=sw0*bfhi(cv.u.x);
    acc[2]=sw0*bflo(cv.u.y); acc[3]=sw0*bfhi(cv.u.y);
    acc[4]=sw0*bflo(cv.u.z); acc[5]=sw0*bfhi(cv.u.z);
    acc[6]=sw0*bflo(cv.u.w); acc[7]=sw0*bfhi(cv.u.w); }
  float denp = 0.f;
  int idxA = g*8 + h;                  // weight lane for edge-offset g   (w0) / 8+g (w1)
  int idxB = idxA + 32;                // weight lane for edge-offset 4+g (w0) / 12+g (w1)
  for (int b = p0u; b < peu; b += 16){
    // weight lanes: edges b+(lane>>3) and b+8+(lane>>3), head wh
    int e0i = b + (lane>>3);
    int e1i = e0i + 8;
    int j0 = e0i < peu ? e0i : peu-1;
    int j1 = e1i < peu ? e1i : peu-1;
    int s0 = csr[j0]; if ((unsigned)s0 >= (unsigned)nn) s0 = 0;
    int s1 = csr[j1]; if ((unsigned)s1 >= (unsigned)nn) s1 = 0;
    float av0 = as1[(size_t)s0*8 + wh];
    float av1 = as1[(size_t)s1*8 + wh];
    float w0 = __expf(fminf(lrelu(av0 + adw), 30.f)) * (e0i < peu ? 1.f : 0.f);
    float w1 = __expf(fminf(lrelu(av1 + adw), 30.f)) * (e1i < peu ? 1.f : 0.f);
    denp += w0 + w1;
    // batch all 4 gathers (edges b+4i+g for i=0..3) to keep MLP
    bf16x8 hv[4]; float wb[4];
    #pragma unroll
    for (int i=0;i<4;++i){
      int sv = __shfl(i < 2 ? s0 : s1, (i & 1) ? idxB : idxA);
      wb[i]  = __shfl(i < 2 ? w0 : w1, (i & 1) ? idxB : idxA);
      hv[i] = *(const bf16x8*)(h1b + (size_t)sv*128 + c0);
    }
    #pragma unroll
    for (int i=0;i<4;++i){
      union { bf16x8 v; uint4 u; } cv; cv.v = hv[i];
      float wv = wb[i];
      acc[0] += wv*bflo(cv.u.x); acc[1] += wv*bfhi(cv.u.x);
      acc[2] += wv*bflo(cv.u.y); acc[3] += wv*bfhi(cv.u.y);
      acc[4] += wv*bflo(cv.u.z); acc[5] += wv*bfhi(cv.u.z);
      acc[6] += wv*bflo(cv.u.w); acc[7] += wv*bfhi(cv.u.w);
    }
  }
  // reduce the 4 redundant group accumulators (all lanes end up with full sums)
  #pragma unroll
  for (int j=0;j<8;++j){
    acc[j] += __shfl_xor(acc[j], 16);
    acc[j] += __shfl_xor(acc[j], 32);
  }
  // denom: sum lanes with same wh (bits 3..5), then fetch my head's total
  denp += __shfl_xor(denp, 8);
  denp += __shfl_xor(denp, 16);
  denp += __shfl_xor(denp, 32);
  float den = __shfl(denp, h) + selfw;
  float inv = 1.f/(den + 1e-16f);
  // residual + bias + LayerNorm + ELU
  bf16x8 xv = *(const bf16x8*)(xr + (size_t)n*128 + c0);
  union { bf16x8 v; uint4 u; } xc; xc.v = xv;
  float xf[8] = { bflo(xc.u.x), bfhi(xc.u.x), bflo(xc.u.y), bfhi(xc.u.y),
                  bflo(xc.u.z), bfhi(xc.u.z), bflo(xc.u.w), bfhi(xc.u.w) };
  float4 bA = *(const float4*)(bias1f + c0), bB = *(const float4*)(bias1f + c0 + 4);
  float bb[8] = { bA.x,bA.y,bA.z,bA.w, bB.x,bB.y,bB.z,bB.w };
  float o[8];
  float s1 = 0.f, s2 = 0.f;
  #pragma unroll
  for (int j=0;j<8;++j){
    o[j] = acc[j]*inv + xf[j] + bb[j];
    s1 += o[j]; s2 += o[j]*o[j];
  }
  // groups hold identical values -> reduce over t bits (0..3) only
  #pragma unroll
  for (int off=1; off<16; off<<=1){
    s1 += __shfl_xor(s1, off);
    s2 += __shfl_xor(s2, off);
  }
  float mu  = s1 * (1.f/128.f);
  float var = s2 * (1.f/128.f) - mu*mu;
  float rstd = rsqrtf(var + 1e-5f);
  float4 gA = *(const float4*)(gf + c0),   gB = *(const float4*)(gf + c0 + 4);
  float4 tA = *(const float4*)(bfta + c0), tB = *(const float4*)(bfta + c0 + 4);
  float gg[8] = { gA.x,gA.y,gA.z,gA.w, gB.x,gB.y,gB.z,gB.w };
  float tt[8] = { tA.x,tA.y,tA.z,tA.w, tB.x,tB.y,tB.z,tB.w };
  #pragma unroll
  for (int j=0;j<8;++j){
    float v = (o[j]-mu)*rstd*gg[j] + tt[j];
    o[j] = v > 0.f ? v : __expf(v) - 1.f;
  }
  if (g == 0){
    if (!f32){
      bf16x8 ov = packbf8((float4){o[0],o[1],o[2],o[3]}, (float4){o[4],o[5],o[6],o[7]});
      *(bf16x8*)((__hip_bfloat16*)dout + (size_t)n*128 + c0) = ov;
    } else {
      float* op = (float*)dout + (size_t)n*128 + c0;
      *(float4*)op     = (float4){o[0],o[1],o[2],o[3]};
      *(float4*)(op+4) = (float4){o[4],o[5],o[6],o[7]};
    }
  }
}

// ---- layer-2 aggregate; 1 wave/node. 16B/lane gathers, 8 groups of 8 lanes,
// 8 edges per 1KB load instr, 8-way-redundant acc reduced with shfl_xor(8,16,32).
__global__ __launch_bounds__(256) void agg2(const __hip_bfloat16* __restrict__ h2b,
    const float* __restrict__ as2, const float* __restrict__ ad2,
    const int* __restrict__ rowp, const int* __restrict__ csr,
    const float* __restrict__ bias2f,
    const int* __restrict__ flag, void* __restrict__ dout, int nn, int Etot){
  int f32 = *flag;
  int w = threadIdx.x >> 6, lane = threadIdx.x & 63;
  int n = blockIdx.x*4 + w;
  if (n >= nn) return;
  int g = lane >> 3, t = lane & 7;     // group, position-in-row
  int c0 = t*8;                        // my 8 channels
  float adst = ad2[n];
  float selfw = __expf(fminf(lrelu(as2[n] + adst), 30.f));
  float sw0 = (g == 0) ? selfw : 0.f;
  bf16x8 hs = *(const bf16x8*)(h2b + (size_t)n*64 + c0);
  float acc[8];
  { union { bf16x8 v; uint4 u; } cv; cv.v = hs;
    acc[0]=sw0*bflo(cv.u.x); acc[1]=sw0*bfhi(cv.u.x);
    acc[2]=sw0*bflo(cv.u.y); acc[3]=sw0*bfhi(cv.u.y);
    acc[4]=sw0*bflo(cv.u.z); acc[5]=sw0*bfhi(cv.u.z);
    acc[6]=sw0*bflo(cv.u.w); acc[7]=sw0*bfhi(cv.u.w); }
  float denp = 0.f;
  int p0 = rowp[n], pe = rowp[n+1];
  if (p0 < 0) p0 = 0; if (pe > Etot) pe = Etot;
  int p0u = __builtin_amdgcn_readfirstlane(p0);
  int peu = __builtin_amdgcn_readfirstlane(pe);
  for (int b = p0u; b < peu; b += 64){
    // weight lanes: edge b+lane
    int ei = b + lane;
    int ji = ei < peu ? ei : peu-1;
    int si = csr[ji]; if ((unsigned)si >= (unsigned)nn) si = 0;
    float av = as2[si];
    float wv = __expf(fminf(lrelu(av + adst), 30.f)) * (ei < peu ? 1.f : 0.f);
    denp += wv;
    #pragma unroll
    for (int ib = 0; ib < 8; ib += 4){
      if (b + 8*ib < peu){             // uniform: skip empty 32-edge half
        bf16x8 hv[4]; float wb[4];
        #pragma unroll
        for (int u=0;u<4;++u){
          int i = ib + u;
          int sv = __shfl(si, g + 8*i);
          wb[u]  = __shfl(wv, g + 8*i);
          hv[u] = *(const bf16x8*)(h2b + (size_t)sv*64 + c0);
        }
        #pragma unroll
        for (int u=0;u<4;++u){
          union { bf16x8 v; uint4 uu; } cv; cv.v = hv[u];
          float wx = wb[u];
          acc[0] += wx*bflo(cv.uu.x); acc[1] += wx*bfhi(cv.uu.x);
          acc[2] += wx*bflo(cv.uu.y); acc[3] += wx*bfhi(cv.uu.y);
          acc[4] += wx*bflo(cv.uu.z); acc[5] += wx*bfhi(cv.uu.z);
          acc[6] += wx*bflo(cv.uu.w); acc[7] += wx*bfhi(cv.uu.w);
        }
      }
    }
  }
  // reduce the 8 redundant group accumulators
  #pragma unroll
  for (int j=0;j<8;++j){
    acc[j] += __shfl_xor(acc[j], 8);
    acc[j] += __shfl_xor(acc[j], 16);
    acc[j] += __shfl_xor(acc[j], 32);
  }
  denp += __shfl_xor(denp, 1);
  denp += __shfl_xor(denp, 2);
  denp += __shfl_xor(denp, 4);
  denp += __shfl_xor(denp, 8);
  denp += __shfl_xor(denp, 16);
  denp += __shfl_xor(denp, 32);
  float den = denp + selfw;
  float inv = 1.f/(den + 1e-16f);
  float4 bA = *(const float4*)(bias2f + c0), bB = *(const float4*)(bias2f + c0 + 4);
  float bb[8] = { bA.x,bA.y,bA.z,bA.w, bB.x,bB.y,bB.z,bB.w };
  float o[8];
  #pragma unroll
  for (int j=0;j<8;++j) o[j] = acc[j]*inv + bb[j];
  if (g == 0){
    if (!f32){
      bf16x8 ov = packbf8((float4){o[0],o[1],o[2],o[3]}, (float4){o[4],o[5],o[6],o[7]});
      *(bf16x8*)((__hip_bfloat16*)dout + (size_t)nn*128 + (size_t)n*64 + c0) = ov;
    } else {
      float* op = (float*)dout + (size_t)nn*128 + (size_t)n*64 + c0;
      *(float4*)op     = (float4){o[0],o[1],o[2],o[3]};
      *(float4*)(op+4) = (float4){o[4],o[5],o[6],o[7]};
    }
  }
}

extern "C" void kernel_launch(void* const* d_in, const int* in_sizes, int n_in,
                              void* d_out, int out_size, void* d_ws, size_t ws_size,
                              hipStream_t stream){
  (void)n_in; (void)out_size;
  const void* x     = d_in[0];
  const int*  ei    = (const int*)d_in[1];
  const void* W1    = d_in[2];
  const void* a1s   = d_in[3];
  const void* a1d   = d_in[4];
  const void* b1    = d_in[5];
  const void* resW  = d_in[6];
  const void* g     = d_in[7];
  const void* bt    = d_in[8];
  const void* W2    = d_in[9];
  const void* a2s   = d_in[10];
  const void* a2d   = d_in[11];
  const void* b2    = d_in[12];

  int N = in_sizes[0] / 128;
  int E = in_sizes[1] / 2;

  __hip_bfloat16* xrB = (__hip_bfloat16*)d_out;
  __hip_bfloat16* xrF = (__hip_bfloat16*)((float*)d_out + (size_t)N*128);

  char* ws = (char*)d_ws;
  size_t o = 0;
  auto alloc = [&](size_t bytes)->char*{ char* r = ws + o; o = (o + bytes + 255) & ~(size_t)255; return r; };
  int*   flag = (int*)  alloc(4);
  int*   part = (int*)  alloc(4096);
  int*   rowp = (int*)  alloc(((size_t)N+1)*4);
  int*   cnt  = (int*)  alloc((size_t)N*4);
  float* as1  = (float*)alloc((size_t)N*8*4);
  float* ad1  = (float*)alloc((size_t)N*8*4);
  int*   csr  = (int*)  alloc((size_t)E*4);
  __hip_bfloat16* h1b = (__hip_bfloat16*)alloc((size_t)N*128*2);
  __hip_bfloat16* Bt1 = (__hip_bfloat16*)alloc(65536);
  __hip_bfloat16* W2t = (__hip_bfloat16*)alloc(16384);
  float* att1s  = (float*)alloc(512);
  float* att1d  = (float*)alloc(512);
  float* bias1f = (float*)alloc(512);
  float* gfv    = (float*)alloc(512);
  float* bfv    = (float*)alloc(512);
  float* att2s  = (float*)alloc(256);
  float* att2d  = (float*)alloc(256);
  float* bias2f = (float*)alloc(256);
  // eoff LAST: if workspace can't fit it, fall back to the atomic fill path
  int*   eoff = (int*)  alloc((size_t)E*4);
  int use_eoff = (o <= ws_size);
  __hip_bfloat16* h2b = h1b;
  float* as2 = as1;
  float* ad2 = ad1;

  int G  = (N + 15)/16;
  int EB = (E + 255)/256;
  int NB = (N + 1023)/1024;

  (void)hipMemsetAsync(flag, 0, 4, stream);
  (void)hipMemsetAsync(cnt,  0, (size_t)N*4, stream);
  detect<<<16, 256, 0, stream>>>((const unsigned short*)x, flag);
  prep<<<164, 256, 0, stream>>>(W1, resW, W2, a1s, a1d, b1, g, bt, a2s, a2d, b2,
                                Bt1, W2t, att1s, att1d, bias1f, gfv, bfv,
                                att2s, att2d, bias2f, flag);
  // GEMM1 + attdot1 epilogue, with count_edges riding as extra blocks
  gemm1_fat<<<G + EB, 256, 0, stream>>>(x, Bt1, h1b, xrB, xrF,
                                        att1s, att1d, as1, ad1,
                                        ei, cnt, use_eoff ? eoff : (int*)nullptr,
                                        flag, N, E, G);
  scan_part<<<NB, 256, 0, stream>>>(cnt, part, N);
  scan_mid<<<1, 256, 0, stream>>>(part, NB, rowp, N);
  scan_write<<<NB, 256, 0, stream>>>(cnt, part, rowp, N);
  if (use_eoff){
    fill_csr<<<EB, 256, 0, stream>>>(ei, rowp, eoff, csr, E, N);
  } else {
    (void)hipMemsetAsync(cnt, 0, (size_t)N*4, stream);
    fill_csr_atomic<<<EB, 256, 0, stream>>>(ei, rowp, cnt, csr, E, N);
  }
  agg1<<<(N+3)/4, 256, 0, stream>>>(h1b, as1, ad1, rowp, csr, xrB, xrF,
                                    bias1f, gfv, bfv, flag, d_out, N, E);
  gemm2_fat<<<G, 256, 0, stream>>>(d_out, W2t, h2b, att2s, att2d, as2, ad2, flag, N);
  agg2<<<(N+3)/4, 256, 0, stream>>>(h2b, as2, ad2, rowp, csr, bias2f, flag, d_out, N, E);
}

// Round 6
// 472.852 us; speedup vs baseline: 1.0725x; 1.0337x over previous
//
#include <hip/hip_runtime.h>
#include <hip/hip_bf16.h>

typedef __attribute__((ext_vector_type(8))) short bf16x8;
typedef __attribute__((ext_vector_type(4))) float f32x4;

__device__ __forceinline__ float bfu(unsigned short u){
  union{ unsigned int i; float f; } c; c.i = ((unsigned)u) << 16; return c.f;
}
__device__ __forceinline__ float bflo(unsigned u){
  union{ unsigned int i; float f; } c; c.i = u << 16; return c.f;
}
__device__ __forceinline__ float bfhi(unsigned u){
  union{ unsigned int i; float f; } c; c.i = u & 0xffff0000u; return c.f;
}
__device__ __forceinline__ float ldval(const void* p, int i, int f32){
  return f32 ? ((const float*)p)[i] : bfu(((const unsigned short*)p)[i]);
}
__device__ __forceinline__ bf16x8 packbf8(float4 u, float4 v){
  union { bf16x8 v8; __hip_bfloat16 h[8]; } r;
  r.h[0]=__float2bfloat16(u.x); r.h[1]=__float2bfloat16(u.y);
  r.h[2]=__float2bfloat16(u.z); r.h[3]=__float2bfloat16(u.w);
  r.h[4]=__float2bfloat16(v.x); r.h[5]=__float2bfloat16(v.y);
  r.h[6]=__float2bfloat16(v.z); r.h[7]=__float2bfloat16(v.w);
  return r.v8;
}
__device__ __forceinline__ float lrelu(float v){ return v > 0.f ? v : 0.2f*v; }

// ---- dtype detect: fp32 data read as bf16 has wild exponents
__global__ void detect(const unsigned short* __restrict__ xh, int* __restrict__ flag){
  int i = blockIdx.x*256 + threadIdx.x;
  float v = fabsf(bfu(xh[i]));
  if (v > 1e4f) atomicOr(flag, 1);
}

// ---- canonicalize weights: Bt1[256][128] = [W1 | resW]^T, W2t[64][128] = W2^T, smalls fp32
__global__ void prep(const void* W1, const void* resW, const void* W2,
                     const void* a1s, const void* a1d, const void* b1,
                     const void* g, const void* bt,
                     const void* a2s, const void* a2d, const void* b2,
                     __hip_bfloat16* __restrict__ Bt1, __hip_bfloat16* __restrict__ W2t,
                     float* att1s, float* att1d, float* bias1f, float* gf, float* bfta,
                     float* att2s, float* att2d, float* bias2f, const int* flag){
  int f = *flag;
  int idx = blockIdx.x*256 + threadIdx.x;
  if (idx < 16384){ int c=idx>>7, k=idx&127; Bt1[idx] = __float2bfloat16(ldval(W1,  k*128+c, f)); }
  else if (idx < 32768){ int i=idx-16384, c=i>>7, k=i&127; Bt1[idx] = __float2bfloat16(ldval(resW,k*128+c, f)); }
  else if (idx < 40960){ int i=idx-32768, c=i>>7, k=i&127; W2t[i]  = __float2bfloat16(ldval(W2,  k*64+c,  f)); }
  else if (idx < 41088) att1s [idx-40960] = ldval(a1s, idx-40960, f);
  else if (idx < 41216) att1d [idx-41088] = ldval(a1d, idx-41088, f);
  else if (idx < 41344) bias1f[idx-41216] = ldval(b1,  idx-41216, f);
  else if (idx < 41472) gf    [idx-41344] = ldval(g,   idx-41344, f);
  else if (idx < 41600) bfta  [idx-41472] = ldval(bt,  idx-41472, f);
  else if (idx < 41664) att2s [idx-41600] = ldval(a2s, idx-41600, f);
  else if (idx < 41728) att2d [idx-41664] = ldval(a2d, idx-41664, f);
  else if (idx < 41792) bias2f[idx-41728] = ldval(b2,  idx-41728, f);
}

// ---- FAT kernel: blocks [0,G) do GEMM1 (+fused attdot1 epilogue);
//      blocks [G, G+128) do B1: per-block bucket histogram (LDS, no global atomics).
__global__ __launch_bounds__(256) void gemm1_fat(const void* __restrict__ xp,
                  const __hip_bfloat16* __restrict__ Bt1,
                  __hip_bfloat16* __restrict__ h1b,
                  __hip_bfloat16* __restrict__ xrB,
                  __hip_bfloat16* __restrict__ xrF,
                  const float* __restrict__ att1s, const float* __restrict__ att1d,
                  float* __restrict__ as1, float* __restrict__ ad1,
                  const int* __restrict__ ei, int* __restrict__ blockCounts,
                  const int* __restrict__ flag, int nn, int E, int G, int s, int NBK){
  __shared__ __hip_bfloat16 sh[16][128];
  __shared__ int histB[1024];
  if ((int)blockIdx.x >= G){
    // ---- B1: bucket-count role (block-uniform branch; barriers OK)
    int cb = (int)blockIdx.x - G;      // 0..127
    int tid = threadIdx.x;
    for (int j = tid; j < 1024; j += 256) histB[j] = 0;
    __syncthreads();
    int chunk = (E + 127) >> 7;
    int start = cb*chunk, end = start + chunk; if (end > E) end = E;
    for (int e = start + tid; e < end; e += 256){
      int d = ei[E+e];
      if ((unsigned)d < (unsigned)nn) atomicAdd(&histB[d >> s], 1);
    }
    __syncthreads();
    for (int j = tid; j < NBK; j += 256) blockCounts[(size_t)j*128 + cb] = histB[j];
    return;
  }
  int f32 = *flag;
  __hip_bfloat16* xr = f32 ? xrF : xrB;
  int wave = threadIdx.x >> 6, lane = threadIdx.x & 63;
  int m = lane & 15, q = lane >> 4;
  int n0 = blockIdx.x * 16;
  int row = n0 + m; if (row >= nn) row = nn - 1;
  f32x4 acc[4];
  #pragma unroll
  for (int ct=0; ct<4; ++ct) acc[ct] = (f32x4){0.f,0.f,0.f,0.f};
  #pragma unroll
  for (int kk=0; kk<4; ++kk){
    bf16x8 a;
    if (!f32) a = *(const bf16x8*)((const __hip_bfloat16*)xp + (size_t)row*128 + kk*32 + q*8);
    else { const float4* fp = (const float4*)((const float*)xp + (size_t)row*128 + kk*32 + q*8);
           a = packbf8(fp[0], fp[1]); }
    #pragma unroll
    for (int ct=0; ct<4; ++ct){
      int c = wave*64 + ct*16 + m;
      bf16x8 b = *(const bf16x8*)(Bt1 + (size_t)c*128 + kk*32 + q*8);
      acc[ct] = __builtin_amdgcn_mfma_f32_16x16x32_bf16(a, b, acc[ct], 0, 0, 0);
    }
  }
  #pragma unroll
  for (int ct=0; ct<4; ++ct){
    int c = wave*64 + ct*16 + m;
    #pragma unroll
    for (int i=0;i<4;++i){
      int r = n0 + q*4 + i;
      if (r < nn){
        __hip_bfloat16 hv = __float2bfloat16(acc[ct][i]);
        if (c < 128){ h1b[(size_t)r*128 + c] = hv; sh[q*4+i][c] = hv; }
        else          xr [(size_t)r*128 + (c-128)] = hv;
      }
    }
  }
  __syncthreads();
  // ---- fused attdot1: threads 0..127 -> (row r, head h) dot from LDS tile
  int tid = threadIdx.x;
  if (tid < 128){
    int r = tid >> 3, h = tid & 7;
    if (n0 + r < nn){
      const bf16x8* hp = (const bf16x8*)&sh[r][h*16];
      bf16x8 v0 = hp[0], v1 = hp[1];
      float sdot=0.f, ddot=0.f;
      #pragma unroll
      for (int j=0;j<8;++j){
        float a = bfu((unsigned short)v0[j]);
        sdot += a*att1s[h*16+j]; ddot += a*att1d[h*16+j];
      }
      #pragma unroll
      for (int j=0;j<8;++j){
        float a = bfu((unsigned short)v1[j]);
        sdot += a*att1s[h*16+8+j]; ddot += a*att1d[h*16+8+j];
      }
      as1[(size_t)(n0+r)*8 + h] = sdot;
      ad1[(size_t)(n0+r)*8 + h] = ddot;
    }
  }
}

// ---- GEMM2 + fused attdot2 epilogue: h2b[N,64] = bf16( h @ W2 )
__global__ __launch_bounds__(256) void gemm2_fat(const void* __restrict__ hp,
                  const __hip_bfloat16* __restrict__ W2t,
                  __hip_bfloat16* __restrict__ h2b,
                  const float* __restrict__ att2s, const float* __restrict__ att2d,
                  float* __restrict__ as2, float* __restrict__ ad2,
                  const int* __restrict__ flag, int nn){
  __shared__ __hip_bfloat16 sh2[16][64];
  int f32 = *flag;
  int wave = threadIdx.x >> 6, lane = threadIdx.x & 63;
  int m = lane & 15, q = lane >> 4;
  int n0 = blockIdx.x * 16;
  int row = n0 + m; if (row >= nn) row = nn - 1;
  f32x4 acc = (f32x4){0.f,0.f,0.f,0.f};
  #pragma unroll
  for (int kk=0; kk<4; ++kk){
    bf16x8 a;
    if (!f32) a = *(const bf16x8*)((const __hip_bfloat16*)hp + (size_t)row*128 + kk*32 + q*8);
    else { const float4* fp = (const float4*)((const float*)hp + (size_t)row*128 + kk*32 + q*8);
           a = packbf8(fp[0], fp[1]); }
    int c = wave*16 + m;
    bf16x8 b = *(const bf16x8*)(W2t + (size_t)c*128 + kk*32 + q*8);
    acc = __builtin_amdgcn_mfma_f32_16x16x32_bf16(a, b, acc, 0, 0, 0);
  }
  int c = wave*16 + m;
  #pragma unroll
  for (int i=0;i<4;++i){
    int r = n0 + q*4 + i;
    if (r < nn){
      __hip_bfloat16 hv = __float2bfloat16(acc[i]);
      h2b[(size_t)r*64 + c] = hv;
      sh2[q*4+i][c] = hv;
    }
  }
  __syncthreads();
  int tid = threadIdx.x;
  if (tid < 16 && n0 + tid < nn){
    const bf16x8* rp = (const bf16x8*)&sh2[tid][0];
    float sdot=0.f, ddot=0.f;
    #pragma unroll
    for (int t=0;t<8;++t){
      bf16x8 v = rp[t];
      #pragma unroll
      for (int j=0;j<8;++j){
        float a = bfu((unsigned short)v[j]);
        sdot += a*att2s[t*8+j]; ddot += a*att2d[t*8+j];
      }
    }
    as2[n0+tid]=sdot; ad2[n0+tid]=ddot;
  }
}

__global__ void scan_part(const int* __restrict__ cnt, int* __restrict__ part, int n){
  __shared__ int red[256];
  int t = threadIdx.x;
  int base = blockIdx.x*1024 + t*4;
  int s = 0;
  #pragma unroll
  for (int j=0;j<4;++j){ int i = base + j; if (i < n) s += cnt[i]; }
  red[t] = s; __syncthreads();
  for (int off=128; off>0; off>>=1){
    if (t < off) red[t] += red[t+off];
    __syncthreads();
  }
  if (t == 0) part[blockIdx.x] = red[0];
}

__global__ void scan_mid(int* __restrict__ part, int nb, int* __restrict__ row_ptr, int n){
  __shared__ int sd[256];
  int t = threadIdx.x;
  int v = (t < nb) ? part[t] : 0;
  sd[t] = v; __syncthreads();
  for (int off=1; off<256; off<<=1){
    int xv = (t >= off) ? sd[t-off] : 0;
    __syncthreads();
    sd[t] += xv;
    __syncthreads();
  }
  if (t < nb) part[t] = sd[t] - v;
  if (t == 0) row_ptr[n] = sd[255];
}

__global__ void scan_write(const int* __restrict__ cnt, const int* __restrict__ part,
                           int* __restrict__ row_ptr, int n){
  __shared__ int sd[256];
  int t = threadIdx.x;
  int base = blockIdx.x*1024 + t*4;
  int v0=0,v1=0,v2=0,v3=0;
  if (base   < n) v0 = cnt[base];
  if (base+1 < n) v1 = cnt[base+1];
  if (base+2 < n) v2 = cnt[base+2];
  if (base+3 < n) v3 = cnt[base+3];
  int s = v0+v1+v2+v3;
  sd[t] = s; __syncthreads();
  for (int off=1; off<256; off<<=1){
    int xv = (t >= off) ? sd[t-off] : 0;
    __syncthreads();
    sd[t] += xv;
    __syncthreads();
  }
  int run = part[blockIdx.x] + sd[t] - s;
  if (base   < n) row_ptr[base]   = run; run += v0;
  if (base+1 < n) row_ptr[base+1] = run; run += v1;
  if (base+2 < n) row_ptr[base+2] = run; run += v2;
  if (base+3 < n) row_ptr[base+3] = run;
}

// ---- B2: scatter edges into bucket-ordered array; LDS cursors from scanned bases.
// Same chunking as B1 -> disjoint slot ranges per (bucket, block). No global atomics.
__global__ __launch_bounds__(256) void bucket_scatter(const int* __restrict__ ei,
                  const int* __restrict__ scanned, unsigned* __restrict__ bucketed,
                  int E, int nn, int s, int NBK){
  __shared__ int cur[1024];
  int cb = blockIdx.x;                 // 0..127
  int tid = threadIdx.x;
  for (int j = tid; j < NBK; j += 256) cur[j] = scanned[(size_t)j*128 + cb];
  __syncthreads();
  int chunk = (E + 127) >> 7;
  int start = cb*chunk, end = start + chunk; if (end > E) end = E;
  for (int e = start + tid; e < end; e += 256){
    int d = ei[E+e];
    if ((unsigned)d >= (unsigned)nn) continue;
    int src = ei[e]; if ((unsigned)src >= (unsigned)nn) src = 0;
    int bk = d >> s;
    int slot = atomicAdd(&cur[bk], 1);
    bucketed[slot] = ((unsigned)src << s) | (unsigned)(d & ((1<<s)-1));
  }
}

// ---- C: per-bucket CSR finalize. One block per bucket: local histogram + prefix
// in LDS, write rowp for its dsts, scatter csr within its contiguous region.
__global__ __launch_bounds__(256) void bucket_csr(const unsigned* __restrict__ bucketed,
                  const int* __restrict__ scanned, int* __restrict__ rowp,
                  int* __restrict__ csr, int nn, int s, int NBK){
  __shared__ int hist[1024];
  __shared__ int sd[256];
  int b = blockIdx.x, tid = threadIdx.x;
  int nloc = 1 << s;
  int dbase = b << s;
  int ndst = nn - dbase; if (ndst > nloc) ndst = nloc;
  int rbeg = scanned[(size_t)b*128];
  int rend = (b+1 < NBK) ? scanned[((size_t)b+1)*128] : rowp[nn];
  for (int j = tid; j < 1024; j += 256) hist[j] = 0;
  __syncthreads();
  for (int i = rbeg + tid; i < rend; i += 256)
    atomicAdd(&hist[bucketed[i] & (nloc-1)], 1);
  __syncthreads();
  int base4 = tid*4;
  int v0=hist[base4], v1=hist[base4+1], v2=hist[base4+2], v3=hist[base4+3];
  int ssum = v0+v1+v2+v3;
  sd[tid]=ssum; __syncthreads();
  for (int off=1; off<256; off<<=1){
    int xv = (tid>=off)? sd[tid-off]:0;
    __syncthreads(); sd[tid]+=xv; __syncthreads();
  }
  int run = sd[tid]-ssum;                  // exclusive base for my 4 entries
  hist[base4]=run; hist[base4+1]=run+v0; hist[base4+2]=run+v0+v1; hist[base4+3]=run+v0+v1+v2;
  #pragma unroll
  for (int k=0;k<4;++k){
    int j = base4+k;
    if (j < ndst) rowp[dbase+j] = rbeg + hist[j];
  }
  __syncthreads();
  for (int i = rbeg + tid; i < rend; i += 256){
    unsigned u = bucketed[i];
    int ld = u & (nloc-1);
    int slot = rbeg + atomicAdd(&hist[ld], 1);
    csr[slot] = (int)(u >> s);
  }
}

// ---- layer-1 aggregate + xres + LayerNorm + ELU; 1 wave/node
// 16B/lane gathers. 4 groups of 16 lanes; group g loads edge (b+4i+g)'s full
// row (16 lanes x 16B = 256B); lane owns 8 fixed channels -> 4-way-redundant acc,
// reduced with shfl_xor(16,32) once per node.
__global__ __launch_bounds__(256) void agg1(
    const __hip_bfloat16* __restrict__ h1b,
    const float* __restrict__ as1, const float* __restrict__ ad1,
    const int* __restrict__ rowp, const int* __restrict__ csr,
    const __hip_bfloat16* __restrict__ xrB, const __hip_bfloat16* __restrict__ xrF,
    const float* __restrict__ bias1f, const float* __restrict__ gf,
    const float* __restrict__ bfta,
    const int* __restrict__ flag, void* __restrict__ dout, int nn, int Etot){
  int f32 = *flag;
  int w = threadIdx.x >> 6, lane = threadIdx.x & 63;
  int n = blockIdx.x*4 + w;
  if (n >= nn) return;
  int g = lane >> 4, t = lane & 15;    // group, position-in-row
  int c0 = t*8;                        // my 8 channels
  int h = t >> 1;                      // my head
  int wh = lane & 7;                   // weight role: head wh
  const __hip_bfloat16* xr = f32 ? xrF : xrB;
  float adc = ad1[n*8 + h];
  float adw = ad1[n*8 + wh];
  float asn = as1[n*8 + h];
  bf16x8 hs = *(const bf16x8*)(h1b + (size_t)n*128 + c0);   // self row, 16B/lane
  int p0 = rowp[n], pe = rowp[n+1];
  if (p0 < 0) p0 = 0; if (pe > Etot) pe = Etot;
  int p0u = __builtin_amdgcn_readfirstlane(p0);
  int peu = __builtin_amdgcn_readfirstlane(pe);
  float selfw = __expf(fminf(lrelu(asn + adc), 30.f));
  float sw0 = (g == 0) ? selfw : 0.f;  // count self-loop in exactly one group
  float acc[8];
  { union { bf16x8 v; uint4 u; } cv; cv.v = hs;
    acc[0]=sw0*bflo(cv.u.x); acc[1]=sw0*bfhi(cv.u.x);
    acc[2]=sw0*bflo(cv.u.y); acc[3]=sw0*bfhi(cv.u.y);
    acc[4]=sw0*bflo(cv.u.z); acc[5]=sw0*bfhi(cv.u.z);
    acc[6]=sw0*bflo(cv.u.w); acc[7]=sw0*bfhi(cv.u.w); }
  float denp = 0.f;
  int idxA = g*8 + h;
  int idxB = idxA + 32;
  for (int b = p0u; b < peu; b += 16){
    int e0i = b + (lane>>3);
    int e1i = e0i + 8;
    int j0 = e0i < peu ? e0i : peu-1;
    int j1 = e1i < peu ? e1i : peu-1;
    int s0 = csr[j0]; if ((unsigned)s0 >= (unsigned)nn) s0 = 0;
    int s1 = csr[j1]; if ((unsigned)s1 >= (unsigned)nn) s1 = 0;
    float av0 = as1[(size_t)s0*8 + wh];
    float av1 = as1[(size_t)s1*8 + wh];
    float w0 = __expf(fminf(lrelu(av0 + adw), 30.f)) * (e0i < peu ? 1.f : 0.f);
    float w1 = __expf(fminf(lrelu(av1 + adw), 30.f)) * (e1i < peu ? 1.f : 0.f);
    denp += w0 + w1;
    bf16x8 hv[4]; float wb[4];
    #pragma unroll
    for (int i=0;i<4;++i){
      int sv = __shfl(i < 2 ? s0 : s1, (i & 1) ? idxB : idxA);
      wb[i]  = __shfl(i < 2 ? w0 : w1, (i & 1) ? idxB : idxA);
      hv[i] = *(const bf16x8*)(h1b + (size_t)sv*128 + c0);
    }
    #pragma unroll
    for (int i=0;i<4;++i){
      union { bf16x8 v; uint4 u; } cv; cv.v = hv[i];
      float wv = wb[i];
      acc[0] += wv*bflo(cv.u.x); acc[1] += wv*bfhi(cv.u.x);
      acc[2] += wv*bflo(cv.u.y); acc[3] += wv*bfhi(cv.u.y);
      acc[4] += wv*bflo(cv.u.z); acc[5] += wv*bfhi(cv.u.z);
      acc[6] += wv*bflo(cv.u.w); acc[7] += wv*bfhi(cv.u.w);
    }
  }
  #pragma unroll
  for (int j=0;j<8;++j){
    acc[j] += __shfl_xor(acc[j], 16);
    acc[j] += __shfl_xor(acc[j], 32);
  }
  denp += __shfl_xor(denp, 8);
  denp += __shfl_xor(denp, 16);
  denp += __shfl_xor(denp, 32);
  float den = __shfl(denp, h) + selfw;
  float inv = 1.f/(den + 1e-16f);
  bf16x8 xv = *(const bf16x8*)(xr + (size_t)n*128 + c0);
  union { bf16x8 v; uint4 u; } xc; xc.v = xv;
  float xf[8] = { bflo(xc.u.x), bfhi(xc.u.x), bflo(xc.u.y), bfhi(xc.u.y),
                  bflo(xc.u.z), bfhi(xc.u.z), bflo(xc.u.w), bfhi(xc.u.w) };
  float4 bA = *(const float4*)(bias1f + c0), bB = *(const float4*)(bias1f + c0 + 4);
  float bb[8] = { bA.x,bA.y,bA.z,bA.w, bB.x,bB.y,bB.z,bB.w };
  float o[8];
  float s1 = 0.f, s2 = 0.f;
  #pragma unroll
  for (int j=0;j<8;++j){
    o[j] = acc[j]*inv + xf[j] + bb[j];
    s1 += o[j]; s2 += o[j]*o[j];
  }
  #pragma unroll
  for (int off=1; off<16; off<<=1){
    s1 += __shfl_xor(s1, off);
    s2 += __shfl_xor(s2, off);
  }
  float mu  = s1 * (1.f/128.f);
  float var = s2 * (1.f/128.f) - mu*mu;
  float rstd = rsqrtf(var + 1e-5f);
  float4 gA = *(const float4*)(gf + c0),   gB = *(const float4*)(gf + c0 + 4);
  float4 tA = *(const float4*)(bfta + c0), tB = *(const float4*)(bfta + c0 + 4);
  float gg[8] = { gA.x,gA.y,gA.z,gA.w, gB.x,gB.y,gB.z,gB.w };
  float tt[8] = { tA.x,tA.y,tA.z,tA.w, tB.x,tB.y,tB.z,tB.w };
  #pragma unroll
  for (int j=0;j<8;++j){
    float v = (o[j]-mu)*rstd*gg[j] + tt[j];
    o[j] = v > 0.f ? v : __expf(v) - 1.f;
  }
  if (g == 0){
    if (!f32){
      bf16x8 ov = packbf8((float4){o[0],o[1],o[2],o[3]}, (float4){o[4],o[5],o[6],o[7]});
      *(bf16x8*)((__hip_bfloat16*)dout + (size_t)n*128 + c0) = ov;
    } else {
      float* op = (float*)dout + (size_t)n*128 + c0;
      *(float4*)op     = (float4){o[0],o[1],o[2],o[3]};
      *(float4*)(op+4) = (float4){o[4],o[5],o[6],o[7]};
    }
  }
}

// ---- layer-2 aggregate; 1 wave/node. 16B/lane gathers, 8 groups of 8 lanes.
__global__ __launch_bounds__(256) void agg2(const __hip_bfloat16* __restrict__ h2b,
    const float* __restrict__ as2, const float* __restrict__ ad2,
    const int* __restrict__ rowp, const int* __restrict__ csr,
    const float* __restrict__ bias2f,
    const int* __restrict__ flag, void* __restrict__ dout, int nn, int Etot){
  int f32 = *flag;
  int w = threadIdx.x >> 6, lane = threadIdx.x & 63;
  int n = blockIdx.x*4 + w;
  if (n >= nn) return;
  int g = lane >> 3, t = lane & 7;
  int c0 = t*8;
  float adst = ad2[n];
  float selfw = __expf(fminf(lrelu(as2[n] + adst), 30.f));
  float sw0 = (g == 0) ? selfw : 0.f;
  bf16x8 hs = *(const bf16x8*)(h2b + (size_t)n*64 + c0);
  float acc[8];
  { union { bf16x8 v; uint4 u; } cv; cv.v = hs;
    acc[0]=sw0*bflo(cv.u.x); acc[1]=sw0*bfhi(cv.u.x);
    acc[2]=sw0*bflo(cv.u.y); acc[3]=sw0*bfhi(cv.u.y);
    acc[4]=sw0*bflo(cv.u.z); acc[5]=sw0*bfhi(cv.u.z);
    acc[6]=sw0*bflo(cv.u.w); acc[7]=sw0*bfhi(cv.u.w); }
  float denp = 0.f;
  int p0 = rowp[n], pe = rowp[n+1];
  if (p0 < 0) p0 = 0; if (pe > Etot) pe = Etot;
  int p0u = __builtin_amdgcn_readfirstlane(p0);
  int peu = __builtin_amdgcn_readfirstlane(pe);
  for (int b = p0u; b < peu; b += 64){
    int ei = b + lane;
    int ji = ei < peu ? ei : peu-1;
    int si = csr[ji]; if ((unsigned)si >= (unsigned)nn) si = 0;
    float av = as2[si];
    float wv = __expf(fminf(lrelu(av + adst), 30.f)) * (ei < peu ? 1.f : 0.f);
    denp += wv;
    #pragma unroll
    for (int ib = 0; ib < 8; ib += 4){
      if (b + 8*ib < peu){             // uniform: skip empty 32-edge half
        bf16x8 hv[4]; float wb[4];
        #pragma unroll
        for (int u=0;u<4;++u){
          int i = ib + u;
          int sv = __shfl(si, g + 8*i);
          wb[u]  = __shfl(wv, g + 8*i);
          hv[u] = *(const bf16x8*)(h2b + (size_t)sv*64 + c0);
        }
        #pragma unroll
        for (int u=0;u<4;++u){
          union { bf16x8 v; uint4 uu; } cv; cv.v = hv[u];
          float wx = wb[u];
          acc[0] += wx*bflo(cv.uu.x); acc[1] += wx*bfhi(cv.uu.x);
          acc[2] += wx*bflo(cv.uu.y); acc[3] += wx*bfhi(cv.uu.y);
          acc[4] += wx*bflo(cv.uu.z); acc[5] += wx*bfhi(cv.uu.z);
          acc[6] += wx*bflo(cv.uu.w); acc[7] += wx*bfhi(cv.uu.w);
        }
      }
    }
  }
  #pragma unroll
  for (int j=0;j<8;++j){
    acc[j] += __shfl_xor(acc[j], 8);
    acc[j] += __shfl_xor(acc[j], 16);
    acc[j] += __shfl_xor(acc[j], 32);
  }
  denp += __shfl_xor(denp, 1);
  denp += __shfl_xor(denp, 2);
  denp += __shfl_xor(denp, 4);
  denp += __shfl_xor(denp, 8);
  denp += __shfl_xor(denp, 16);
  denp += __shfl_xor(denp, 32);
  float den = denp + selfw;
  float inv = 1.f/(den + 1e-16f);
  float4 bA = *(const float4*)(bias2f + c0), bB = *(const float4*)(bias2f + c0 + 4);
  float bb[8] = { bA.x,bA.y,bA.z,bA.w, bB.x,bB.y,bB.z,bB.w };
  float o[8];
  #pragma unroll
  for (int j=0;j<8;++j) o[j] = acc[j]*inv + bb[j];
  if (g == 0){
    if (!f32){
      bf16x8 ov = packbf8((float4){o[0],o[1],o[2],o[3]}, (float4){o[4],o[5],o[6],o[7]});
      *(bf16x8*)((__hip_bfloat16*)dout + (size_t)nn*128 + (size_t)n*64 + c0) = ov;
    } else {
      float* op = (float*)dout + (size_t)nn*128 + (size_t)n*64 + c0;
      *(float4*)op     = (float4){o[0],o[1],o[2],o[3]};
      *(float4*)(op+4) = (float4){o[4],o[5],o[6],o[7]};
    }
  }
}

extern "C" void kernel_launch(void* const* d_in, const int* in_sizes, int n_in,
                              void* d_out, int out_size, void* d_ws, size_t ws_size,
                              hipStream_t stream){
  (void)n_in; (void)out_size; (void)ws_size;
  const void* x     = d_in[0];
  const int*  ei    = (const int*)d_in[1];
  const void* W1    = d_in[2];
  const void* a1s   = d_in[3];
  const void* a1d   = d_in[4];
  const void* b1    = d_in[5];
  const void* resW  = d_in[6];
  const void* g     = d_in[7];
  const void* bt    = d_in[8];
  const void* W2    = d_in[9];
  const void* a2s   = d_in[10];
  const void* a2d   = d_in[11];
  const void* b2    = d_in[12];

  int N = in_sizes[0] / 128;
  int E = in_sizes[1] / 2;

  // bucket shift: smallest s (>=7) with ceil(N/2^s) <= 1024 buckets
  int s = 7;
  while ((((size_t)N + ((size_t)1 << s) - 1) >> s) > 1024) ++s;
  int NBK = (N + (1 << s) - 1) >> s;
  int M = NBK * 128;                   // blockCounts / scanned length

  __hip_bfloat16* xrB = (__hip_bfloat16*)d_out;
  __hip_bfloat16* xrF = (__hip_bfloat16*)((float*)d_out + (size_t)N*128);

  char* ws = (char*)d_ws;
  size_t o = 0;
  auto alloc = [&](size_t bytes)->char*{ char* r = ws + o; o = (o + bytes + 255) & ~(size_t)255; return r; };
  int*   flag = (int*)  alloc(4);
  int*   part = (int*)  alloc(4096);
  int*   rowp = (int*)  alloc(((size_t)N+1)*4);
  float* as1  = (float*)alloc((size_t)N*8*4);
  float* ad1  = (float*)alloc((size_t)N*8*4);
  int*   csr  = (int*)  alloc((size_t)E*4);
  unsigned* bucketed = (unsigned*)alloc((size_t)E*4);
  int*   blockCounts = (int*)alloc((size_t)M*4);
  int*   scanned     = (int*)alloc((size_t)M*4);
  __hip_bfloat16* h1b = (__hip_bfloat16*)alloc((size_t)N*128*2);
  __hip_bfloat16* Bt1 = (__hip_bfloat16*)alloc(65536);
  __hip_bfloat16* W2t = (__hip_bfloat16*)alloc(16384);
  float* att1s  = (float*)alloc(512);
  float* att1d  = (float*)alloc(512);
  float* bias1f = (float*)alloc(512);
  float* gfv    = (float*)alloc(512);
  float* bfv    = (float*)alloc(512);
  float* att2s  = (float*)alloc(256);
  float* att2d  = (float*)alloc(256);
  float* bias2f = (float*)alloc(256);
  __hip_bfloat16* h2b = h1b;
  float* as2 = as1;
  float* ad2 = ad1;

  int G  = (N + 15)/16;
  int NBscan = (M + 1023)/1024;

  (void)hipMemsetAsync(flag, 0, 4, stream);
  detect<<<16, 256, 0, stream>>>((const unsigned short*)x, flag);
  prep<<<164, 256, 0, stream>>>(W1, resW, W2, a1s, a1d, b1, g, bt, a2s, a2d, b2,
                                Bt1, W2t, att1s, att1d, bias1f, gfv, bfv,
                                att2s, att2d, bias2f, flag);
  // GEMM1 + attdot1 epilogue, with B1 bucket-count riding as 128 extra blocks
  gemm1_fat<<<G + 128, 256, 0, stream>>>(x, Bt1, h1b, xrB, xrF,
                                         att1s, att1d, as1, ad1,
                                         ei, blockCounts, flag, N, E, G, s, NBK);
  // exclusive scan of blockCounts (length M); total -> rowp[N]
  scan_part<<<NBscan, 256, 0, stream>>>(blockCounts, part, M);
  scan_mid<<<1, 256, 0, stream>>>(part, NBscan, rowp, N);
  scan_write<<<NBscan, 256, 0, stream>>>(blockCounts, part, scanned, M);
  bucket_scatter<<<128, 256, 0, stream>>>(ei, scanned, bucketed, E, N, s, NBK);
  bucket_csr<<<NBK, 256, 0, stream>>>(bucketed, scanned, rowp, csr, N, s, NBK);
  agg1<<<(N+3)/4, 256, 0, stream>>>(h1b, as1, ad1, rowp, csr, xrB, xrF,
                                    bias1f, gfv, bfv, flag, d_out, N, E);
  gemm2_fat<<<G, 256, 0, stream>>>(d_out, W2t, h2b, att2s, att2d, as2, ad2, flag, N);
  agg2<<<(N+3)/4, 256, 0, stream>>>(h2b, as2, ad2, rowp, csr, bias2f, flag, d_out, N, E);
}

// Round 7
// 427.934 us; speedup vs baseline: 1.1851x; 1.1050x over previous
//
#include <hip/hip_runtime.h>
#include <hip/hip_bf16.h>

typedef __attribute__((ext_vector_type(8))) short bf16x8;
typedef __attribute__((ext_vector_type(4))) float f32x4;

__device__ __forceinline__ float bfu(unsigned short u){
  union{ unsigned int i; float f; } c; c.i = ((unsigned)u) << 16; return c.f;
}
__device__ __forceinline__ float bflo(unsigned u){
  union{ unsigned int i; float f; } c; c.i = u << 16; return c.f;
}
__device__ __forceinline__ float bfhi(unsigned u){
  union{ unsigned int i; float f; } c; c.i = u & 0xffff0000u; return c.f;
}
__device__ __forceinline__ float ldval(const void* p, int i, int f32){
  return f32 ? ((const float*)p)[i] : bfu(((const unsigned short*)p)[i]);
}
__device__ __forceinline__ bf16x8 packbf8(float4 u, float4 v){
  union { bf16x8 v8; __hip_bfloat16 h[8]; } r;
  r.h[0]=__float2bfloat16(u.x); r.h[1]=__float2bfloat16(u.y);
  r.h[2]=__float2bfloat16(u.z); r.h[3]=__float2bfloat16(u.w);
  r.h[4]=__float2bfloat16(v.x); r.h[5]=__float2bfloat16(v.y);
  r.h[6]=__float2bfloat16(v.z); r.h[7]=__float2bfloat16(v.w);
  return r.v8;
}
__device__ __forceinline__ float lrelu(float v){ return v > 0.f ? v : 0.2f*v; }

// ---- dtype detect: fp32 data read as bf16 has wild exponents
__global__ void detect(const unsigned short* __restrict__ xh, int* __restrict__ flag){
  int i = blockIdx.x*256 + threadIdx.x;
  float v = fabsf(bfu(xh[i]));
  if (v > 1e4f) atomicOr(flag, 1);
}

// ---- canonicalize weights: Bt1[256][128] = [W1 | resW]^T, W2t[64][128] = W2^T, smalls fp32
__global__ void prep(const void* W1, const void* resW, const void* W2,
                     const void* a1s, const void* a1d, const void* b1,
                     const void* g, const void* bt,
                     const void* a2s, const void* a2d, const void* b2,
                     __hip_bfloat16* __restrict__ Bt1, __hip_bfloat16* __restrict__ W2t,
                     float* att1s, float* att1d, float* bias1f, float* gf, float* bfta,
                     float* att2s, float* att2d, float* bias2f, const int* flag){
  int f = *flag;
  int idx = blockIdx.x*256 + threadIdx.x;
  if (idx < 16384){ int c=idx>>7, k=idx&127; Bt1[idx] = __float2bfloat16(ldval(W1,  k*128+c, f)); }
  else if (idx < 32768){ int i=idx-16384, c=i>>7, k=i&127; Bt1[idx] = __float2bfloat16(ldval(resW,k*128+c, f)); }
  else if (idx < 40960){ int i=idx-32768, c=i>>7, k=i&127; W2t[i]  = __float2bfloat16(ldval(W2,  k*64+c,  f)); }
  else if (idx < 41088) att1s [idx-40960] = ldval(a1s, idx-40960, f);
  else if (idx < 41216) att1d [idx-41088] = ldval(a1d, idx-41088, f);
  else if (idx < 41344) bias1f[idx-41216] = ldval(b1,  idx-41216, f);
  else if (idx < 41472) gf    [idx-41344] = ldval(g,   idx-41344, f);
  else if (idx < 41600) bfta  [idx-41472] = ldval(bt,  idx-41472, f);
  else if (idx < 41664) att2s [idx-41600] = ldval(a2s, idx-41600, f);
  else if (idx < 41728) att2d [idx-41664] = ldval(a2d, idx-41664, f);
  else if (idx < 41792) bias2f[idx-41728] = ldval(b2,  idx-41728, f);
}

// ---- FAT kernel: blocks [0,128) do B1 (per-block bucket histogram, LDS) so they
//      START FIRST and hide under the GEMM; blocks [128, 128+G) do GEMM1 (+attdot1).
__global__ __launch_bounds__(256) void gemm1_fat(const void* __restrict__ xp,
                  const __hip_bfloat16* __restrict__ Bt1,
                  __hip_bfloat16* __restrict__ h1b,
                  __hip_bfloat16* __restrict__ xrB,
                  __hip_bfloat16* __restrict__ xrF,
                  const float* __restrict__ att1s, const float* __restrict__ att1d,
                  float* __restrict__ as1, float* __restrict__ ad1,
                  const int* __restrict__ ei, int* __restrict__ blockCounts,
                  const int* __restrict__ flag, int nn, int E, int G, int s, int NBK){
  __shared__ __hip_bfloat16 sh[16][128];
  __shared__ int histB[1024];
  if ((int)blockIdx.x < 128){
    // ---- B1: bucket-count role (first blocks -> overlap with GEMM role)
    int cb = (int)blockIdx.x;          // 0..127
    int tid = threadIdx.x;
    for (int j = tid; j < 1024; j += 256) histB[j] = 0;
    __syncthreads();
    int chunk = (((E + 127) >> 7) + 3) & ~3;   // 4-aligned chunk
    int start = cb*chunk, end = start + chunk; if (end > E) end = E;
    if ((E & 3) == 0 && start < end){
      int e = start + tid*4;
      for (; e + 4 <= end; e += 1024){
        int4 dd = *(const int4*)&ei[E+e];
        if ((unsigned)dd.x < (unsigned)nn) atomicAdd(&histB[dd.x >> s], 1);
        if ((unsigned)dd.y < (unsigned)nn) atomicAdd(&histB[dd.y >> s], 1);
        if ((unsigned)dd.z < (unsigned)nn) atomicAdd(&histB[dd.z >> s], 1);
        if ((unsigned)dd.w < (unsigned)nn) atomicAdd(&histB[dd.w >> s], 1);
      }
      for (; e < end; ++e){
        int d = ei[E+e];
        if ((unsigned)d < (unsigned)nn) atomicAdd(&histB[d >> s], 1);
      }
    } else {
      for (int e = start + tid; e < end; e += 256){
        int d = ei[E+e];
        if ((unsigned)d < (unsigned)nn) atomicAdd(&histB[d >> s], 1);
      }
    }
    __syncthreads();
    for (int j = tid; j < NBK; j += 256) blockCounts[(size_t)j*128 + cb] = histB[j];
    return;
  }
  int bid = (int)blockIdx.x - 128;
  int f32 = *flag;
  __hip_bfloat16* xr = f32 ? xrF : xrB;
  int wave = threadIdx.x >> 6, lane = threadIdx.x & 63;
  int m = lane & 15, q = lane >> 4;
  int n0 = bid * 16;
  int row = n0 + m; if (row >= nn) row = nn - 1;
  f32x4 acc[4];
  #pragma unroll
  for (int ct=0; ct<4; ++ct) acc[ct] = (f32x4){0.f,0.f,0.f,0.f};
  #pragma unroll
  for (int kk=0; kk<4; ++kk){
    bf16x8 a;
    if (!f32) a = *(const bf16x8*)((const __hip_bfloat16*)xp + (size_t)row*128 + kk*32 + q*8);
    else { const float4* fp = (const float4*)((const float*)xp + (size_t)row*128 + kk*32 + q*8);
           a = packbf8(fp[0], fp[1]); }
    #pragma unroll
    for (int ct=0; ct<4; ++ct){
      int c = wave*64 + ct*16 + m;
      bf16x8 b = *(const bf16x8*)(Bt1 + (size_t)c*128 + kk*32 + q*8);
      acc[ct] = __builtin_amdgcn_mfma_f32_16x16x32_bf16(a, b, acc[ct], 0, 0, 0);
    }
  }
  #pragma unroll
  for (int ct=0; ct<4; ++ct){
    int c = wave*64 + ct*16 + m;
    #pragma unroll
    for (int i=0;i<4;++i){
      int r = n0 + q*4 + i;
      if (r < nn){
        __hip_bfloat16 hv = __float2bfloat16(acc[ct][i]);
        if (c < 128){ h1b[(size_t)r*128 + c] = hv; sh[q*4+i][c] = hv; }
        else          xr [(size_t)r*128 + (c-128)] = hv;
      }
    }
  }
  __syncthreads();
  // ---- fused attdot1: threads 0..127 -> (row r, head h) dot from LDS tile
  int tid = threadIdx.x;
  if (tid < 128){
    int r = tid >> 3, h = tid & 7;
    if (n0 + r < nn){
      const bf16x8* hp = (const bf16x8*)&sh[r][h*16];
      bf16x8 v0 = hp[0], v1 = hp[1];
      float sdot=0.f, ddot=0.f;
      #pragma unroll
      for (int j=0;j<8;++j){
        float a = bfu((unsigned short)v0[j]);
        sdot += a*att1s[h*16+j]; ddot += a*att1d[h*16+j];
      }
      #pragma unroll
      for (int j=0;j<8;++j){
        float a = bfu((unsigned short)v1[j]);
        sdot += a*att1s[h*16+8+j]; ddot += a*att1d[h*16+8+j];
      }
      as1[(size_t)(n0+r)*8 + h] = sdot;
      ad1[(size_t)(n0+r)*8 + h] = ddot;
    }
  }
}

// ---- GEMM2 + fused attdot2 epilogue: h2b[N,64] = bf16( h @ W2 )
__global__ __launch_bounds__(256) void gemm2_fat(const void* __restrict__ hp,
                  const __hip_bfloat16* __restrict__ W2t,
                  __hip_bfloat16* __restrict__ h2b,
                  const float* __restrict__ att2s, const float* __restrict__ att2d,
                  float* __restrict__ as2, float* __restrict__ ad2,
                  const int* __restrict__ flag, int nn){
  __shared__ __hip_bfloat16 sh2[16][64];
  int f32 = *flag;
  int wave = threadIdx.x >> 6, lane = threadIdx.x & 63;
  int m = lane & 15, q = lane >> 4;
  int n0 = blockIdx.x * 16;
  int row = n0 + m; if (row >= nn) row = nn - 1;
  f32x4 acc = (f32x4){0.f,0.f,0.f,0.f};
  #pragma unroll
  for (int kk=0; kk<4; ++kk){
    bf16x8 a;
    if (!f32) a = *(const bf16x8*)((const __hip_bfloat16*)hp + (size_t)row*128 + kk*32 + q*8);
    else { const float4* fp = (const float4*)((const float*)hp + (size_t)row*128 + kk*32 + q*8);
           a = packbf8(fp[0], fp[1]); }
    int c = wave*16 + m;
    bf16x8 b = *(const bf16x8*)(W2t + (size_t)c*128 + kk*32 + q*8);
    acc = __builtin_amdgcn_mfma_f32_16x16x32_bf16(a, b, acc, 0, 0, 0);
  }
  int c = wave*16 + m;
  #pragma unroll
  for (int i=0;i<4;++i){
    int r = n0 + q*4 + i;
    if (r < nn){
      __hip_bfloat16 hv = __float2bfloat16(acc[i]);
      h2b[(size_t)r*64 + c] = hv;
      sh2[q*4+i][c] = hv;
    }
  }
  __syncthreads();
  int tid = threadIdx.x;
  if (tid < 16 && n0 + tid < nn){
    const bf16x8* rp = (const bf16x8*)&sh2[tid][0];
    float sdot=0.f, ddot=0.f;
    #pragma unroll
    for (int t=0;t<8;++t){
      bf16x8 v = rp[t];
      #pragma unroll
      for (int j=0;j<8;++j){
        float a = bfu((unsigned short)v[j]);
        sdot += a*att2s[t*8+j]; ddot += a*att2d[t*8+j];
      }
    }
    as2[n0+tid]=sdot; ad2[n0+tid]=ddot;
  }
}

__global__ void scan_part(const int* __restrict__ cnt, int* __restrict__ part, int n){
  __shared__ int red[256];
  int t = threadIdx.x;
  int base = blockIdx.x*1024 + t*4;
  int s = 0;
  #pragma unroll
  for (int j=0;j<4;++j){ int i = base + j; if (i < n) s += cnt[i]; }
  red[t] = s; __syncthreads();
  for (int off=128; off>0; off>>=1){
    if (t < off) red[t] += red[t+off];
    __syncthreads();
  }
  if (t == 0) part[blockIdx.x] = red[0];
}

__global__ void scan_mid(int* __restrict__ part, int nb, int* __restrict__ row_ptr, int n){
  __shared__ int sd[256];
  int t = threadIdx.x;
  int v = (t < nb) ? part[t] : 0;
  sd[t] = v; __syncthreads();
  for (int off=1; off<256; off<<=1){
    int xv = (t >= off) ? sd[t-off] : 0;
    __syncthreads();
    sd[t] += xv;
    __syncthreads();
  }
  if (t < nb) part[t] = sd[t] - v;
  if (t == 0) row_ptr[n] = sd[255];
}

__global__ void scan_write(const int* __restrict__ cnt, const int* __restrict__ part,
                           int* __restrict__ row_ptr, int n){
  __shared__ int sd[256];
  int t = threadIdx.x;
  int base = blockIdx.x*1024 + t*4;
  int v0=0,v1=0,v2=0,v3=0;
  if (base   < n) v0 = cnt[base];
  if (base+1 < n) v1 = cnt[base+1];
  if (base+2 < n) v2 = cnt[base+2];
  if (base+3 < n) v3 = cnt[base+3];
  int s = v0+v1+v2+v3;
  sd[t] = s; __syncthreads();
  for (int off=1; off<256; off<<=1){
    int xv = (t >= off) ? sd[t-off] : 0;
    __syncthreads();
    sd[t] += xv;
    __syncthreads();
  }
  int run = part[blockIdx.x] + sd[t] - s;
  if (base   < n) row_ptr[base]   = run; run += v0;
  if (base+1 < n) row_ptr[base+1] = run; run += v1;
  if (base+2 < n) row_ptr[base+2] = run; run += v2;
  if (base+3 < n) row_ptr[base+3] = run;
}

// ---- B2: scatter edges into bucket-ordered array; LDS cursors from scanned bases.
// Same chunking as B1 -> disjoint slot ranges per (bucket, block). No global atomics.
__global__ __launch_bounds__(256) void bucket_scatter(const int* __restrict__ ei,
                  const int* __restrict__ scanned, unsigned* __restrict__ bucketed,
                  int E, int nn, int s, int NBK){
  __shared__ int cur[1024];
  int cb = blockIdx.x;                 // 0..127
  int tid = threadIdx.x;
  for (int j = tid; j < NBK; j += 256) cur[j] = scanned[(size_t)j*128 + cb];
  __syncthreads();
  int chunk = (((E + 127) >> 7) + 3) & ~3;
  int start = cb*chunk, end = start + chunk; if (end > E) end = E;
  unsigned lmask = (1u << s) - 1u;
  if ((E & 3) == 0 && start < end){
    int e = start + tid*4;
    for (; e + 4 <= end; e += 1024){
      int4 dd = *(const int4*)&ei[E+e];
      int4 ss = *(const int4*)&ei[e];
      #pragma unroll
      for (int k=0;k<4;++k){
        int d = (&dd.x)[k];
        if ((unsigned)d >= (unsigned)nn) continue;
        int src = (&ss.x)[k]; if ((unsigned)src >= (unsigned)nn) src = 0;
        int slot = atomicAdd(&cur[d >> s], 1);
        bucketed[slot] = ((unsigned)src << s) | ((unsigned)d & lmask);
      }
    }
    for (; e < end; ++e){
      int d = ei[E+e];
      if ((unsigned)d >= (unsigned)nn) continue;
      int src = ei[e]; if ((unsigned)src >= (unsigned)nn) src = 0;
      int slot = atomicAdd(&cur[d >> s], 1);
      bucketed[slot] = ((unsigned)src << s) | ((unsigned)d & lmask);
    }
  } else {
    for (int e = start + tid; e < end; e += 256){
      int d = ei[E+e];
      if ((unsigned)d >= (unsigned)nn) continue;
      int src = ei[e]; if ((unsigned)src >= (unsigned)nn) src = 0;
      int slot = atomicAdd(&cur[d >> s], 1);
      bucketed[slot] = ((unsigned)src << s) | ((unsigned)d & lmask);
    }
  }
}

// ---- C: per-bucket CSR finalize. One block per bucket: local histogram + prefix
// in LDS, write rowp for its dsts, scatter csr within its contiguous region.
__global__ __launch_bounds__(256) void bucket_csr(const unsigned* __restrict__ bucketed,
                  const int* __restrict__ scanned, int* __restrict__ rowp,
                  int* __restrict__ csr, int nn, int s, int NBK){
  __shared__ int hist[1024];
  __shared__ int sd[256];
  int b = blockIdx.x, tid = threadIdx.x;
  int nloc = 1 << s;
  int dbase = b << s;
  int ndst = nn - dbase; if (ndst > nloc) ndst = nloc;
  int rbeg = scanned[(size_t)b*128];
  int rend = (b+1 < NBK) ? scanned[((size_t)b+1)*128] : rowp[nn];
  for (int j = tid; j < 1024; j += 256) hist[j] = 0;
  __syncthreads();
  for (int i = rbeg + tid; i < rend; i += 256)
    atomicAdd(&hist[bucketed[i] & (nloc-1)], 1);
  __syncthreads();
  int base4 = tid*4;
  int v0=hist[base4], v1=hist[base4+1], v2=hist[base4+2], v3=hist[base4+3];
  int ssum = v0+v1+v2+v3;
  sd[tid]=ssum; __syncthreads();
  for (int off=1; off<256; off<<=1){
    int xv = (tid>=off)? sd[tid-off]:0;
    __syncthreads(); sd[tid]+=xv; __syncthreads();
  }
  int run = sd[tid]-ssum;                  // exclusive base for my 4 entries
  hist[base4]=run; hist[base4+1]=run+v0; hist[base4+2]=run+v0+v1; hist[base4+3]=run+v0+v1+v2;
  #pragma unroll
  for (int k=0;k<4;++k){
    int j = base4+k;
    if (j < ndst) rowp[dbase+j] = rbeg + hist[j];
  }
  __syncthreads();
  for (int i = rbeg + tid; i < rend; i += 256){
    unsigned u = bucketed[i];
    int ld = u & (nloc-1);
    int slot = rbeg + atomicAdd(&hist[ld], 1);
    csr[slot] = (int)(u >> s);
  }
}

// ---- layer-1 aggregate + xres + LayerNorm + ELU; 1 wave/node
// 16B/lane gathers. 4 groups of 16 lanes; group g loads edge (b+4i+g)'s full
// row (16 lanes x 16B = 256B); lane owns 8 fixed channels -> 4-way-redundant acc,
// reduced with shfl_xor(16,32) once per node.
__global__ __launch_bounds__(256) void agg1(
    const __hip_bfloat16* __restrict__ h1b,
    const float* __restrict__ as1, const float* __restrict__ ad1,
    const int* __restrict__ rowp, const int* __restrict__ csr,
    const __hip_bfloat16* __restrict__ xrB, const __hip_bfloat16* __restrict__ xrF,
    const float* __restrict__ bias1f, const float* __restrict__ gf,
    const float* __restrict__ bfta,
    const int* __restrict__ flag, void* __restrict__ dout, int nn, int Etot){
  int f32 = *flag;
  int w = threadIdx.x >> 6, lane = threadIdx.x & 63;
  int n = blockIdx.x*4 + w;
  if (n >= nn) return;
  int g = lane >> 4, t = lane & 15;    // group, position-in-row
  int c0 = t*8;                        // my 8 channels
  int h = t >> 1;                      // my head
  int wh = lane & 7;                   // weight role: head wh
  const __hip_bfloat16* xr = f32 ? xrF : xrB;
  float adc = ad1[n*8 + h];
  float adw = ad1[n*8 + wh];
  float asn = as1[n*8 + h];
  bf16x8 hs = *(const bf16x8*)(h1b + (size_t)n*128 + c0);   // self row, 16B/lane
  int p0 = rowp[n], pe = rowp[n+1];
  if (p0 < 0) p0 = 0; if (pe > Etot) pe = Etot;
  int p0u = __builtin_amdgcn_readfirstlane(p0);
  int peu = __builtin_amdgcn_readfirstlane(pe);
  float selfw = __expf(fminf(lrelu(asn + adc), 30.f));
  float sw0 = (g == 0) ? selfw : 0.f;  // count self-loop in exactly one group
  float acc[8];
  { union { bf16x8 v; uint4 u; } cv; cv.v = hs;
    acc[0]=sw0*bflo(cv.u.x); acc[1]=sw0*bfhi(cv.u.x);
    acc[2]=sw0*bflo(cv.u.y); acc[3]=sw0*bfhi(cv.u.y);
    acc[4]=sw0*bflo(cv.u.z); acc[5]=sw0*bfhi(cv.u.z);
    acc[6]=sw0*bflo(cv.u.w); acc[7]=sw0*bfhi(cv.u.w); }
  float denp = 0.f;
  int idxA = g*8 + h;
  int idxB = idxA + 32;
  for (int b = p0u; b < peu; b += 16){
    int e0i = b + (lane>>3);
    int e1i = e0i + 8;
    int j0 = e0i < peu ? e0i : peu-1;
    int j1 = e1i < peu ? e1i : peu-1;
    int s0 = csr[j0]; if ((unsigned)s0 >= (unsigned)nn) s0 = 0;
    int s1 = csr[j1]; if ((unsigned)s1 >= (unsigned)nn) s1 = 0;
    float av0 = as1[(size_t)s0*8 + wh];
    float av1 = as1[(size_t)s1*8 + wh];
    float w0 = __expf(fminf(lrelu(av0 + adw), 30.f)) * (e0i < peu ? 1.f : 0.f);
    float w1 = __expf(fminf(lrelu(av1 + adw), 30.f)) * (e1i < peu ? 1.f : 0.f);
    denp += w0 + w1;
    bf16x8 hv[4]; float wb[4];
    #pragma unroll
    for (int i=0;i<4;++i){
      int sv = __shfl(i < 2 ? s0 : s1, (i & 1) ? idxB : idxA);
      wb[i]  = __shfl(i < 2 ? w0 : w1, (i & 1) ? idxB : idxA);
      hv[i] = *(const bf16x8*)(h1b + (size_t)sv*128 + c0);
    }
    #pragma unroll
    for (int i=0;i<4;++i){
      union { bf16x8 v; uint4 u; } cv; cv.v = hv[i];
      float wv = wb[i];
      acc[0] += wv*bflo(cv.u.x); acc[1] += wv*bfhi(cv.u.x);
      acc[2] += wv*bflo(cv.u.y); acc[3] += wv*bfhi(cv.u.y);
      acc[4] += wv*bflo(cv.u.z); acc[5] += wv*bfhi(cv.u.z);
      acc[6] += wv*bflo(cv.u.w); acc[7] += wv*bfhi(cv.u.w);
    }
  }
  #pragma unroll
  for (int j=0;j<8;++j){
    acc[j] += __shfl_xor(acc[j], 16);
    acc[j] += __shfl_xor(acc[j], 32);
  }
  denp += __shfl_xor(denp, 8);
  denp += __shfl_xor(denp, 16);
  denp += __shfl_xor(denp, 32);
  float den = __shfl(denp, h) + selfw;
  float inv = 1.f/(den + 1e-16f);
  bf16x8 xv = *(const bf16x8*)(xr + (size_t)n*128 + c0);
  union { bf16x8 v; uint4 u; } xc; xc.v = xv;
  float xf[8] = { bflo(xc.u.x), bfhi(xc.u.x), bflo(xc.u.y), bfhi(xc.u.y),
                  bflo(xc.u.z), bfhi(xc.u.z), bflo(xc.u.w), bfhi(xc.u.w) };
  float4 bA = *(const float4*)(bias1f + c0), bB = *(const float4*)(bias1f + c0 + 4);
  float bb[8] = { bA.x,bA.y,bA.z,bA.w, bB.x,bB.y,bB.z,bB.w };
  float o[8];
  float s1 = 0.f, s2 = 0.f;
  #pragma unroll
  for (int j=0;j<8;++j){
    o[j] = acc[j]*inv + xf[j] + bb[j];
    s1 += o[j]; s2 += o[j]*o[j];
  }
  #pragma unroll
  for (int off=1; off<16; off<<=1){
    s1 += __shfl_xor(s1, off);
    s2 += __shfl_xor(s2, off);
  }
  float mu  = s1 * (1.f/128.f);
  float var = s2 * (1.f/128.f) - mu*mu;
  float rstd = rsqrtf(var + 1e-5f);
  float4 gA = *(const float4*)(gf + c0),   gB = *(const float4*)(gf + c0 + 4);
  float4 tA = *(const float4*)(bfta + c0), tB = *(const float4*)(bfta + c0 + 4);
  float gg[8] = { gA.x,gA.y,gA.z,gA.w, gB.x,gB.y,gB.z,gB.w };
  float tt[8] = { tA.x,tA.y,tA.z,tA.w, tB.x,tB.y,tB.z,tB.w };
  #pragma unroll
  for (int j=0;j<8;++j){
    float v = (o[j]-mu)*rstd*gg[j] + tt[j];
    o[j] = v > 0.f ? v : __expf(v) - 1.f;
  }
  if (g == 0){
    if (!f32){
      bf16x8 ov = packbf8((float4){o[0],o[1],o[2],o[3]}, (float4){o[4],o[5],o[6],o[7]});
      *(bf16x8*)((__hip_bfloat16*)dout + (size_t)n*128 + c0) = ov;
    } else {
      float* op = (float*)dout + (size_t)n*128 + c0;
      *(float4*)op     = (float4){o[0],o[1],o[2],o[3]};
      *(float4*)(op+4) = (float4){o[4],o[5],o[6],o[7]};
    }
  }
}

// ---- layer-2 aggregate; 1 wave/node. 16B/lane gathers, 8 groups of 8 lanes.
__global__ __launch_bounds__(256) void agg2(const __hip_bfloat16* __restrict__ h2b,
    const float* __restrict__ as2, const float* __restrict__ ad2,
    const int* __restrict__ rowp, const int* __restrict__ csr,
    const float* __restrict__ bias2f,
    const int* __restrict__ flag, void* __restrict__ dout, int nn, int Etot){
  int f32 = *flag;
  int w = threadIdx.x >> 6, lane = threadIdx.x & 63;
  int n = blockIdx.x*4 + w;
  if (n >= nn) return;
  int g = lane >> 3, t = lane & 7;
  int c0 = t*8;
  float adst = ad2[n];
  float selfw = __expf(fminf(lrelu(as2[n] + adst), 30.f));
  float sw0 = (g == 0) ? selfw : 0.f;
  bf16x8 hs = *(const bf16x8*)(h2b + (size_t)n*64 + c0);
  float acc[8];
  { union { bf16x8 v; uint4 u; } cv; cv.v = hs;
    acc[0]=sw0*bflo(cv.u.x); acc[1]=sw0*bfhi(cv.u.x);
    acc[2]=sw0*bflo(cv.u.y); acc[3]=sw0*bfhi(cv.u.y);
    acc[4]=sw0*bflo(cv.u.z); acc[5]=sw0*bfhi(cv.u.z);
    acc[6]=sw0*bflo(cv.u.w); acc[7]=sw0*bfhi(cv.u.w); }
  float denp = 0.f;
  int p0 = rowp[n], pe = rowp[n+1];
  if (p0 < 0) p0 = 0; if (pe > Etot) pe = Etot;
  int p0u = __builtin_amdgcn_readfirstlane(p0);
  int peu = __builtin_amdgcn_readfirstlane(pe);
  for (int b = p0u; b < peu; b += 64){
    int ei = b + lane;
    int ji = ei < peu ? ei : peu-1;
    int si = csr[ji]; if ((unsigned)si >= (unsigned)nn) si = 0;
    float av = as2[si];
    float wv = __expf(fminf(lrelu(av + adst), 30.f)) * (ei < peu ? 1.f : 0.f);
    denp += wv;
    #pragma unroll
    for (int ib = 0; ib < 8; ib += 4){
      if (b + 8*ib < peu){             // uniform: skip empty 32-edge half
        bf16x8 hv[4]; float wb[4];
        #pragma unroll
        for (int u=0;u<4;++u){
          int i = ib + u;
          int sv = __shfl(si, g + 8*i);
          wb[u]  = __shfl(wv, g + 8*i);
          hv[u] = *(const bf16x8*)(h2b + (size_t)sv*64 + c0);
        }
        #pragma unroll
        for (int u=0;u<4;++u){
          union { bf16x8 v; uint4 uu; } cv; cv.v = hv[u];
          float wx = wb[u];
          acc[0] += wx*bflo(cv.uu.x); acc[1] += wx*bfhi(cv.uu.x);
          acc[2] += wx*bflo(cv.uu.y); acc[3] += wx*bfhi(cv.uu.y);
          acc[4] += wx*bflo(cv.uu.z); acc[5] += wx*bfhi(cv.uu.z);
          acc[6] += wx*bflo(cv.uu.w); acc[7] += wx*bfhi(cv.uu.w);
        }
      }
    }
  }
  #pragma unroll
  for (int j=0;j<8;++j){
    acc[j] += __shfl_xor(acc[j], 8);
    acc[j] += __shfl_xor(acc[j], 16);
    acc[j] += __shfl_xor(acc[j], 32);
  }
  denp += __shfl_xor(denp, 1);
  denp += __shfl_xor(denp, 2);
  denp += __shfl_xor(denp, 4);
  denp += __shfl_xor(denp, 8);
  denp += __shfl_xor(denp, 16);
  denp += __shfl_xor(denp, 32);
  float den = denp + selfw;
  float inv = 1.f/(den + 1e-16f);
  float4 bA = *(const float4*)(bias2f + c0), bB = *(const float4*)(bias2f + c0 + 4);
  float bb[8] = { bA.x,bA.y,bA.z,bA.w, bB.x,bB.y,bB.z,bB.w };
  float o[8];
  #pragma unroll
  for (int j=0;j<8;++j) o[j] = acc[j]*inv + bb[j];
  if (g == 0){
    if (!f32){
      bf16x8 ov = packbf8((float4){o[0],o[1],o[2],o[3]}, (float4){o[4],o[5],o[6],o[7]});
      *(bf16x8*)((__hip_bfloat16*)dout + (size_t)nn*128 + (size_t)n*64 + c0) = ov;
    } else {
      float* op = (float*)dout + (size_t)nn*128 + (size_t)n*64 + c0;
      *(float4*)op     = (float4){o[0],o[1],o[2],o[3]};
      *(float4*)(op+4) = (float4){o[4],o[5],o[6],o[7]};
    }
  }
}

extern "C" void kernel_launch(void* const* d_in, const int* in_sizes, int n_in,
                              void* d_out, int out_size, void* d_ws, size_t ws_size,
                              hipStream_t stream){
  (void)n_in; (void)out_size; (void)ws_size;
  const void* x     = d_in[0];
  const int*  ei    = (const int*)d_in[1];
  const void* W1    = d_in[2];
  const void* a1s   = d_in[3];
  const void* a1d   = d_in[4];
  const void* b1    = d_in[5];
  const void* resW  = d_in[6];
  const void* g     = d_in[7];
  const void* bt    = d_in[8];
  const void* W2    = d_in[9];
  const void* a2s   = d_in[10];
  const void* a2d   = d_in[11];
  const void* b2    = d_in[12];

  int N = in_sizes[0] / 128;
  int E = in_sizes[1] / 2;

  // bucket shift: smallest s (>=7) with ceil(N/2^s) <= 1024 buckets
  int s = 7;
  while ((((size_t)N + ((size_t)1 << s) - 1) >> s) > 1024) ++s;
  int NBK = (N + (1 << s) - 1) >> s;
  int M = NBK * 128;                   // blockCounts / scanned length

  __hip_bfloat16* xrB = (__hip_bfloat16*)d_out;
  __hip_bfloat16* xrF = (__hip_bfloat16*)((float*)d_out + (size_t)N*128);

  char* ws = (char*)d_ws;
  size_t o = 0;
  auto alloc = [&](size_t bytes)->char*{ char* r = ws + o; o = (o + bytes + 255) & ~(size_t)255; return r; };
  int*   flag = (int*)  alloc(4);
  int*   part = (int*)  alloc(4096);
  int*   rowp = (int*)  alloc(((size_t)N+1)*4);
  float* as1  = (float*)alloc((size_t)N*8*4);
  float* ad1  = (float*)alloc((size_t)N*8*4);
  int*   csr  = (int*)  alloc((size_t)E*4);
  unsigned* bucketed = (unsigned*)alloc((size_t)E*4);
  int*   blockCounts = (int*)alloc((size_t)M*4);
  int*   scanned     = (int*)alloc((size_t)M*4);
  __hip_bfloat16* h1b = (__hip_bfloat16*)alloc((size_t)N*128*2);
  __hip_bfloat16* Bt1 = (__hip_bfloat16*)alloc(65536);
  __hip_bfloat16* W2t = (__hip_bfloat16*)alloc(16384);
  float* att1s  = (float*)alloc(512);
  float* att1d  = (float*)alloc(512);
  float* bias1f = (float*)alloc(512);
  float* gfv    = (float*)alloc(512);
  float* bfv    = (float*)alloc(512);
  float* att2s  = (float*)alloc(256);
  float* att2d  = (float*)alloc(256);
  float* bias2f = (float*)alloc(256);
  __hip_bfloat16* h2b = h1b;
  float* as2 = as1;
  float* ad2 = ad1;

  int G  = (N + 15)/16;
  int NBscan = (M + 1023)/1024;

  (void)hipMemsetAsync(flag, 0, 4, stream);
  detect<<<16, 256, 0, stream>>>((const unsigned short*)x, flag);
  prep<<<164, 256, 0, stream>>>(W1, resW, W2, a1s, a1d, b1, g, bt, a2s, a2d, b2,
                                Bt1, W2t, att1s, att1d, bias1f, gfv, bfv,
                                att2s, att2d, bias2f, flag);
  // B1 bucket-count rides FIRST (blocks 0..127) so it overlaps the GEMM role
  gemm1_fat<<<128 + G, 256, 0, stream>>>(x, Bt1, h1b, xrB, xrF,
                                         att1s, att1d, as1, ad1,
                                         ei, blockCounts, flag, N, E, G, s, NBK);
  // exclusive scan of blockCounts (length M); total -> rowp[N]
  scan_part<<<NBscan, 256, 0, stream>>>(blockCounts, part, M);
  scan_mid<<<1, 256, 0, stream>>>(part, NBscan, rowp, N);
  scan_write<<<NBscan, 256, 0, stream>>>(blockCounts, part, scanned, M);
  bucket_scatter<<<128, 256, 0, stream>>>(ei, scanned, bucketed, E, N, s, NBK);
  bucket_csr<<<NBK, 256, 0, stream>>>(bucketed, scanned, rowp, csr, N, s, NBK);
  agg1<<<(N+3)/4, 256, 0, stream>>>(h1b, as1, ad1, rowp, csr, xrB, xrF,
                                    bias1f, gfv, bfv, flag, d_out, N, E);
  gemm2_fat<<<G, 256, 0, stream>>>(d_out, W2t, h2b, att2s, att2d, as2, ad2, flag, N);
  agg2<<<(N+3)/4, 256, 0, stream>>>(h2b, as2, ad2, rowp, csr, bias2f, flag, d_out, N, E);
}

// Round 8
// 391.457 us; speedup vs baseline: 1.2956x; 1.0932x over previous
//
#include <hip/hip_runtime.h>
#include <hip/hip_bf16.h>

typedef __attribute__((ext_vector_type(8))) short bf16x8;
typedef __attribute__((ext_vector_type(4))) float f32x4;

__device__ __forceinline__ float bfu(unsigned short u){
  union{ unsigned int i; float f; } c; c.i = ((unsigned)u) << 16; return c.f;
}
__device__ __forceinline__ float bflo(unsigned u){
  union{ unsigned int i; float f; } c; c.i = u << 16; return c.f;
}
__device__ __forceinline__ float bfhi(unsigned u){
  union{ unsigned int i; float f; } c; c.i = u & 0xffff0000u; return c.f;
}
__device__ __forceinline__ float ldval(const void* p, int i, int f32){
  return f32 ? ((const float*)p)[i] : bfu(((const unsigned short*)p)[i]);
}
__device__ __forceinline__ bf16x8 packbf8(float4 u, float4 v){
  union { bf16x8 v8; __hip_bfloat16 h[8]; } r;
  r.h[0]=__float2bfloat16(u.x); r.h[1]=__float2bfloat16(u.y);
  r.h[2]=__float2bfloat16(u.z); r.h[3]=__float2bfloat16(u.w);
  r.h[4]=__float2bfloat16(v.x); r.h[5]=__float2bfloat16(v.y);
  r.h[6]=__float2bfloat16(v.z); r.h[7]=__float2bfloat16(v.w);
  return r.v8;
}
__device__ __forceinline__ float lrelu(float v){ return v > 0.f ? v : 0.2f*v; }

// ---- dtype detect: fp32 data read as bf16 has wild exponents
__global__ void detect(const unsigned short* __restrict__ xh, int* __restrict__ flag){
  int i = blockIdx.x*256 + threadIdx.x;
  float v = fabsf(bfu(xh[i]));
  if (v > 1e4f) atomicOr(flag, 1);
}

// ---- canonicalize weights into FRAGMENT-MAJOR layouts:
// Bt1p: fragment (wave,ct,kk) is 1KB contiguous, lane-linear 16B chunks.
//   pos(c,k): wave=c>>6, ct=(c>>4)&3, m=c&15, kk=k>>5, q=(k>>3)&3, j=k&7
//   frag = ((wave*4+ct)*4+kk)*64 + q*16 + m;  Bt1p[frag*8+j] = [W1|resW]^T[c][k]
// W2tp: frag2 = (wave*4+kk)*64 + q*16 + m (c=wave*16+m, c<64)
__global__ void prep(const void* W1, const void* resW, const void* W2,
                     const void* a1s, const void* a1d, const void* b1,
                     const void* g, const void* bt,
                     const void* a2s, const void* a2d, const void* b2,
                     __hip_bfloat16* __restrict__ Bt1, __hip_bfloat16* __restrict__ W2t,
                     float* att1s, float* att1d, float* bias1f, float* gf, float* bfta,
                     float* att2s, float* att2d, float* bias2f, const int* flag){
  int f = *flag;
  int idx = blockIdx.x*256 + threadIdx.x;
  if (idx < 32768){
    int c = idx >> 7, k = idx & 127;         // c in [0,256), k in [0,128)
    float v = (c < 128) ? ldval(W1, k*128 + c, f) : ldval(resW, k*128 + (c-128), f);
    int wave = c >> 6, ct = (c >> 4) & 3, m = c & 15;
    int kk = k >> 5, q = (k >> 3) & 3, j = k & 7;
    int frag = ((wave*4 + ct)*4 + kk)*64 + q*16 + m;
    Bt1[frag*8 + j] = __float2bfloat16(v);
  }
  else if (idx < 40960){
    int i = idx - 32768;
    int c = i >> 7, k = i & 127;             // c in [0,64)
    float v = ldval(W2, k*64 + c, f);
    int wave = c >> 4, m = c & 15;
    int kk = k >> 5, q = (k >> 3) & 3, j = k & 7;
    int frag = (wave*4 + kk)*64 + q*16 + m;
    W2t[frag*8 + j] = __float2bfloat16(v);
  }
  else if (idx < 41088) att1s [idx-40960] = ldval(a1s, idx-40960, f);
  else if (idx < 41216) att1d [idx-41088] = ldval(a1d, idx-41088, f);
  else if (idx < 41344) bias1f[idx-41216] = ldval(b1,  idx-41216, f);
  else if (idx < 41472) gf    [idx-41344] = ldval(g,   idx-41344, f);
  else if (idx < 41600) bfta  [idx-41472] = ldval(bt,  idx-41472, f);
  else if (idx < 41664) att2s [idx-41600] = ldval(a2s, idx-41600, f);
  else if (idx < 41728) att2d [idx-41664] = ldval(a2d, idx-41664, f);
  else if (idx < 41792) bias2f[idx-41728] = ldval(b2,  idx-41728, f);
}

// ---- FAT kernel: blocks [0,128) do B1 (bucket histogram) FIRST to overlap;
//      blocks [128, 128+G) do GEMM1 (+attdot1), fragment-major B loads,
//      LDS-staged vectorized stores.
__global__ __launch_bounds__(256) void gemm1_fat(const void* __restrict__ xp,
                  const __hip_bfloat16* __restrict__ Bt1,
                  __hip_bfloat16* __restrict__ h1b,
                  __hip_bfloat16* __restrict__ xrB,
                  __hip_bfloat16* __restrict__ xrF,
                  const float* __restrict__ att1s, const float* __restrict__ att1d,
                  float* __restrict__ as1, float* __restrict__ ad1,
                  const int* __restrict__ ei, int* __restrict__ blockCounts,
                  const int* __restrict__ flag, int nn, int E, int G, int s, int NBK){
  __shared__ __hip_bfloat16 sh[16][136];     // h1 tile, padded (272B row, 16B-aligned)
  __shared__ __hip_bfloat16 shx[16][136];    // xres tile
  __shared__ int histB[1024];
  if ((int)blockIdx.x < 128){
    int cb = (int)blockIdx.x;
    int tid = threadIdx.x;
    for (int j = tid; j < 1024; j += 256) histB[j] = 0;
    __syncthreads();
    int chunk = (((E + 127) >> 7) + 3) & ~3;
    int start = cb*chunk, end = start + chunk; if (end > E) end = E;
    if ((E & 3) == 0 && start < end){
      int e = start + tid*4;
      for (; e + 4 <= end; e += 1024){
        int4 dd = *(const int4*)&ei[E+e];
        if ((unsigned)dd.x < (unsigned)nn) atomicAdd(&histB[dd.x >> s], 1);
        if ((unsigned)dd.y < (unsigned)nn) atomicAdd(&histB[dd.y >> s], 1);
        if ((unsigned)dd.z < (unsigned)nn) atomicAdd(&histB[dd.z >> s], 1);
        if ((unsigned)dd.w < (unsigned)nn) atomicAdd(&histB[dd.w >> s], 1);
      }
      for (; e < end; ++e){
        int d = ei[E+e];
        if ((unsigned)d < (unsigned)nn) atomicAdd(&histB[d >> s], 1);
      }
    } else {
      for (int e = start + tid; e < end; e += 256){
        int d = ei[E+e];
        if ((unsigned)d < (unsigned)nn) atomicAdd(&histB[d >> s], 1);
      }
    }
    __syncthreads();
    for (int j = tid; j < NBK; j += 256) blockCounts[(size_t)j*128 + cb] = histB[j];
    return;
  }
  int bid = (int)blockIdx.x - 128;
  int f32 = *flag;
  __hip_bfloat16* xr = f32 ? xrF : xrB;
  int wave = threadIdx.x >> 6, lane = threadIdx.x & 63;
  int m = lane & 15, q = lane >> 4;
  int n0 = bid * 16;
  int row = n0 + m; if (row >= nn) row = nn - 1;
  f32x4 acc[4];
  #pragma unroll
  for (int ct=0; ct<4; ++ct) acc[ct] = (f32x4){0.f,0.f,0.f,0.f};
  const bf16x8* Bf = (const bf16x8*)Bt1;
  #pragma unroll
  for (int kk=0; kk<4; ++kk){
    bf16x8 a;
    if (!f32) a = *(const bf16x8*)((const __hip_bfloat16*)xp + (size_t)row*128 + kk*32 + q*8);
    else { const float4* fp = (const float4*)((const float*)xp + (size_t)row*128 + kk*32 + q*8);
           a = packbf8(fp[0], fp[1]); }
    #pragma unroll
    for (int ct=0; ct<4; ++ct){
      // fragment-major: one fully-coalesced 1KB load per (wave,ct,kk)
      bf16x8 b = Bf[((wave*4 + ct)*4 + kk)*64 + lane];
      acc[ct] = __builtin_amdgcn_mfma_f32_16x16x32_bf16(a, b, acc[ct], 0, 0, 0);
    }
  }
  // stage tile in LDS (no global scalar stores)
  #pragma unroll
  for (int ct=0; ct<4; ++ct){
    int c = wave*64 + ct*16 + m;
    #pragma unroll
    for (int i=0;i<4;++i){
      __hip_bfloat16 hv = __float2bfloat16(acc[ct][i]);
      int r4 = q*4 + i;
      if (c < 128) sh [r4][c]     = hv;
      else         shx[r4][c-128] = hv;
    }
  }
  __syncthreads();
  // vectorized stores: thread t writes 16B of row (t>>4)
  {
    int r = threadIdx.x >> 4, cc = (threadIdx.x & 15)*8;
    if (n0 + r < nn){
      *(bf16x8*)(h1b + (size_t)(n0+r)*128 + cc) = *(const bf16x8*)&sh [r][cc];
      *(bf16x8*)(xr  + (size_t)(n0+r)*128 + cc) = *(const bf16x8*)&shx[r][cc];
    }
  }
  // fused attdot1: threads 0..127 -> (row r, head h) dot from LDS tile
  int tid = threadIdx.x;
  if (tid < 128){
    int r = tid >> 3, h = tid & 7;
    if (n0 + r < nn){
      const bf16x8* hp = (const bf16x8*)&sh[r][h*16];
      bf16x8 v0 = hp[0], v1 = hp[1];
      float sdot=0.f, ddot=0.f;
      #pragma unroll
      for (int j=0;j<8;++j){
        float a = bfu((unsigned short)v0[j]);
        sdot += a*att1s[h*16+j]; ddot += a*att1d[h*16+j];
      }
      #pragma unroll
      for (int j=0;j<8;++j){
        float a = bfu((unsigned short)v1[j]);
        sdot += a*att1s[h*16+8+j]; ddot += a*att1d[h*16+8+j];
      }
      as1[(size_t)(n0+r)*8 + h] = sdot;
      ad1[(size_t)(n0+r)*8 + h] = ddot;
    }
  }
}

// ---- GEMM2 + fused attdot2 epilogue: h2b[N,64] = bf16( h @ W2 ), frag-major W2t
__global__ __launch_bounds__(256) void gemm2_fat(const void* __restrict__ hp,
                  const __hip_bfloat16* __restrict__ W2t,
                  __hip_bfloat16* __restrict__ h2b,
                  const float* __restrict__ att2s, const float* __restrict__ att2d,
                  float* __restrict__ as2, float* __restrict__ ad2,
                  const int* __restrict__ flag, int nn){
  __shared__ __hip_bfloat16 sh2[16][72];
  int f32 = *flag;
  int wave = threadIdx.x >> 6, lane = threadIdx.x & 63;
  int m = lane & 15, q = lane >> 4;
  int n0 = blockIdx.x * 16;
  int row = n0 + m; if (row >= nn) row = nn - 1;
  f32x4 acc = (f32x4){0.f,0.f,0.f,0.f};
  const bf16x8* Wf = (const bf16x8*)W2t;
  #pragma unroll
  for (int kk=0; kk<4; ++kk){
    bf16x8 a;
    if (!f32) a = *(const bf16x8*)((const __hip_bfloat16*)hp + (size_t)row*128 + kk*32 + q*8);
    else { const float4* fp = (const float4*)((const float*)hp + (size_t)row*128 + kk*32 + q*8);
           a = packbf8(fp[0], fp[1]); }
    bf16x8 b = Wf[(wave*4 + kk)*64 + lane];
    acc = __builtin_amdgcn_mfma_f32_16x16x32_bf16(a, b, acc, 0, 0, 0);
  }
  int c = wave*16 + m;
  #pragma unroll
  for (int i=0;i<4;++i) sh2[q*4+i][c] = __float2bfloat16(acc[i]);
  __syncthreads();
  int tid = threadIdx.x;
  if (tid < 128){
    int r = tid >> 3, cc = (tid & 7)*8;
    if (n0 + r < nn)
      *(bf16x8*)(h2b + (size_t)(n0+r)*64 + cc) = *(const bf16x8*)&sh2[r][cc];
  }
  if (tid < 16 && n0 + tid < nn){
    const bf16x8* rp = (const bf16x8*)&sh2[tid][0];
    float sdot=0.f, ddot=0.f;
    #pragma unroll
    for (int t=0;t<8;++t){
      bf16x8 v = rp[t];
      #pragma unroll
      for (int j=0;j<8;++j){
        float a = bfu((unsigned short)v[j]);
        sdot += a*att2s[t*8+j]; ddot += a*att2d[t*8+j];
      }
    }
    as2[n0+tid]=sdot; ad2[n0+tid]=ddot;
  }
}

__global__ void scan_part(const int* __restrict__ cnt, int* __restrict__ part, int n){
  __shared__ int red[256];
  int t = threadIdx.x;
  int base = blockIdx.x*1024 + t*4;
  int s = 0;
  #pragma unroll
  for (int j=0;j<4;++j){ int i = base + j; if (i < n) s += cnt[i]; }
  red[t] = s; __syncthreads();
  for (int off=128; off>0; off>>=1){
    if (t < off) red[t] += red[t+off];
    __syncthreads();
  }
  if (t == 0) part[blockIdx.x] = red[0];
}

__global__ void scan_mid(int* __restrict__ part, int nb, int* __restrict__ row_ptr, int n){
  __shared__ int sd[256];
  int t = threadIdx.x;
  int v = (t < nb) ? part[t] : 0;
  sd[t] = v; __syncthreads();
  for (int off=1; off<256; off<<=1){
    int xv = (t >= off) ? sd[t-off] : 0;
    __syncthreads();
    sd[t] += xv;
    __syncthreads();
  }
  if (t < nb) part[t] = sd[t] - v;
  if (t == 0) row_ptr[n] = sd[255];
}

__global__ void scan_write(const int* __restrict__ cnt, const int* __restrict__ part,
                           int* __restrict__ row_ptr, int n){
  __shared__ int sd[256];
  int t = threadIdx.x;
  int base = blockIdx.x*1024 + t*4;
  int v0=0,v1=0,v2=0,v3=0;
  if (base   < n) v0 = cnt[base];
  if (base+1 < n) v1 = cnt[base+1];
  if (base+2 < n) v2 = cnt[base+2];
  if (base+3 < n) v3 = cnt[base+3];
  int s = v0+v1+v2+v3;
  sd[t] = s; __syncthreads();
  for (int off=1; off<256; off<<=1){
    int xv = (t >= off) ? sd[t-off] : 0;
    __syncthreads();
    sd[t] += xv;
    __syncthreads();
  }
  int run = part[blockIdx.x] + sd[t] - s;
  if (base   < n) row_ptr[base]   = run; run += v0;
  if (base+1 < n) row_ptr[base+1] = run; run += v1;
  if (base+2 < n) row_ptr[base+2] = run; run += v2;
  if (base+3 < n) row_ptr[base+3] = run;
}

// ---- B2: scatter edges into bucket-ordered array; LDS cursors from scanned bases.
__global__ __launch_bounds__(256) void bucket_scatter(const int* __restrict__ ei,
                  const int* __restrict__ scanned, unsigned* __restrict__ bucketed,
                  int E, int nn, int s, int NBK){
  __shared__ int cur[1024];
  int cb = blockIdx.x;
  int tid = threadIdx.x;
  for (int j = tid; j < NBK; j += 256) cur[j] = scanned[(size_t)j*128 + cb];
  __syncthreads();
  int chunk = (((E + 127) >> 7) + 3) & ~3;
  int start = cb*chunk, end = start + chunk; if (end > E) end = E;
  unsigned lmask = (1u << s) - 1u;
  if ((E & 3) == 0 && start < end){
    int e = start + tid*4;
    for (; e + 4 <= end; e += 1024){
      int4 dd = *(const int4*)&ei[E+e];
      int4 ss = *(const int4*)&ei[e];
      #pragma unroll
      for (int k=0;k<4;++k){
        int d = (&dd.x)[k];
        if ((unsigned)d >= (unsigned)nn) continue;
        int src = (&ss.x)[k]; if ((unsigned)src >= (unsigned)nn) src = 0;
        int slot = atomicAdd(&cur[d >> s], 1);
        bucketed[slot] = ((unsigned)src << s) | ((unsigned)d & lmask);
      }
    }
    for (; e < end; ++e){
      int d = ei[E+e];
      if ((unsigned)d >= (unsigned)nn) continue;
      int src = ei[e]; if ((unsigned)src >= (unsigned)nn) src = 0;
      int slot = atomicAdd(&cur[d >> s], 1);
      bucketed[slot] = ((unsigned)src << s) | ((unsigned)d & lmask);
    }
  } else {
    for (int e = start + tid; e < end; e += 256){
      int d = ei[E+e];
      if ((unsigned)d >= (unsigned)nn) continue;
      int src = ei[e]; if ((unsigned)src >= (unsigned)nn) src = 0;
      int slot = atomicAdd(&cur[d >> s], 1);
      bucketed[slot] = ((unsigned)src << s) | ((unsigned)d & lmask);
    }
  }
}

// ---- C: per-bucket CSR finalize.
__global__ __launch_bounds__(256) void bucket_csr(const unsigned* __restrict__ bucketed,
                  const int* __restrict__ scanned, int* __restrict__ rowp,
                  int* __restrict__ csr, int nn, int s, int NBK){
  __shared__ int hist[1024];
  __shared__ int sd[256];
  int b = blockIdx.x, tid = threadIdx.x;
  int nloc = 1 << s;
  int dbase = b << s;
  int ndst = nn - dbase; if (ndst > nloc) ndst = nloc;
  int rbeg = scanned[(size_t)b*128];
  int rend = (b+1 < NBK) ? scanned[((size_t)b+1)*128] : rowp[nn];
  for (int j = tid; j < 1024; j += 256) hist[j] = 0;
  __syncthreads();
  for (int i = rbeg + tid; i < rend; i += 256)
    atomicAdd(&hist[bucketed[i] & (nloc-1)], 1);
  __syncthreads();
  int base4 = tid*4;
  int v0=hist[base4], v1=hist[base4+1], v2=hist[base4+2], v3=hist[base4+3];
  int ssum = v0+v1+v2+v3;
  sd[tid]=ssum; __syncthreads();
  for (int off=1; off<256; off<<=1){
    int xv = (tid>=off)? sd[tid-off]:0;
    __syncthreads(); sd[tid]+=xv; __syncthreads();
  }
  int run = sd[tid]-ssum;
  hist[base4]=run; hist[base4+1]=run+v0; hist[base4+2]=run+v0+v1; hist[base4+3]=run+v0+v1+v2;
  #pragma unroll
  for (int k=0;k<4;++k){
    int j = base4+k;
    if (j < ndst) rowp[dbase+j] = rbeg + hist[j];
  }
  __syncthreads();
  for (int i = rbeg + tid; i < rend; i += 256){
    unsigned u = bucketed[i];
    int ld = u & (nloc-1);
    int slot = rbeg + atomicAdd(&hist[ld], 1);
    csr[slot] = (int)(u >> s);
  }
}

// ---- layer-1 aggregate + xres + LayerNorm + ELU; 1 wave/node
__global__ __launch_bounds__(256) void agg1(
    const __hip_bfloat16* __restrict__ h1b,
    const float* __restrict__ as1, const float* __restrict__ ad1,
    const int* __restrict__ rowp, const int* __restrict__ csr,
    const __hip_bfloat16* __restrict__ xrB, const __hip_bfloat16* __restrict__ xrF,
    const float* __restrict__ bias1f, const float* __restrict__ gf,
    const float* __restrict__ bfta,
    const int* __restrict__ flag, void* __restrict__ dout, int nn, int Etot){
  int f32 = *flag;
  int w = threadIdx.x >> 6, lane = threadIdx.x & 63;
  int n = blockIdx.x*4 + w;
  if (n >= nn) return;
  int g = lane >> 4, t = lane & 15;
  int c0 = t*8;
  int h = t >> 1;
  int wh = lane & 7;
  const __hip_bfloat16* xr = f32 ? xrF : xrB;
  float adc = ad1[n*8 + h];
  float adw = ad1[n*8 + wh];
  float asn = as1[n*8 + h];
  bf16x8 hs = *(const bf16x8*)(h1b + (size_t)n*128 + c0);
  int p0 = rowp[n], pe = rowp[n+1];
  if (p0 < 0) p0 = 0; if (pe > Etot) pe = Etot;
  int p0u = __builtin_amdgcn_readfirstlane(p0);
  int peu = __builtin_amdgcn_readfirstlane(pe);
  float selfw = __expf(fminf(lrelu(asn + adc), 30.f));
  float sw0 = (g == 0) ? selfw : 0.f;
  float acc[8];
  { union { bf16x8 v; uint4 u; } cv; cv.v = hs;
    acc[0]=sw0*bflo(cv.u.x); acc[1]=sw0*bfhi(cv.u.x);
    acc[2]=sw0*bflo(cv.u.y); acc[3]=sw0*bfhi(cv.u.y);
    acc[4]=sw0*bflo(cv.u.z); acc[5]=sw0*bfhi(cv.u.z);
    acc[6]=sw0*bflo(cv.u.w); acc[7]=sw0*bfhi(cv.u.w); }
  float denp = 0.f;
  int idxA = g*8 + h;
  int idxB = idxA + 32;
  for (int b = p0u; b < peu; b += 16){
    int e0i = b + (lane>>3);
    int e1i = e0i + 8;
    int j0 = e0i < peu ? e0i : peu-1;
    int j1 = e1i < peu ? e1i : peu-1;
    int s0 = csr[j0]; if ((unsigned)s0 >= (unsigned)nn) s0 = 0;
    int s1 = csr[j1]; if ((unsigned)s1 >= (unsigned)nn) s1 = 0;
    float av0 = as1[(size_t)s0*8 + wh];
    float av1 = as1[(size_t)s1*8 + wh];
    float w0 = __expf(fminf(lrelu(av0 + adw), 30.f)) * (e0i < peu ? 1.f : 0.f);
    float w1 = __expf(fminf(lrelu(av1 + adw), 30.f)) * (e1i < peu ? 1.f : 0.f);
    denp += w0 + w1;
    bf16x8 hv[4]; float wb[4];
    #pragma unroll
    for (int i=0;i<4;++i){
      int sv = __shfl(i < 2 ? s0 : s1, (i & 1) ? idxB : idxA);
      wb[i]  = __shfl(i < 2 ? w0 : w1, (i & 1) ? idxB : idxA);
      hv[i] = *(const bf16x8*)(h1b + (size_t)sv*128 + c0);
    }
    #pragma unroll
    for (int i=0;i<4;++i){
      union { bf16x8 v; uint4 u; } cv; cv.v = hv[i];
      float wv = wb[i];
      acc[0] += wv*bflo(cv.u.x); acc[1] += wv*bfhi(cv.u.x);
      acc[2] += wv*bflo(cv.u.y); acc[3] += wv*bfhi(cv.u.y);
      acc[4] += wv*bflo(cv.u.z); acc[5] += wv*bfhi(cv.u.z);
      acc[6] += wv*bflo(cv.u.w); acc[7] += wv*bfhi(cv.u.w);
    }
  }
  #pragma unroll
  for (int j=0;j<8;++j){
    acc[j] += __shfl_xor(acc[j], 16);
    acc[j] += __shfl_xor(acc[j], 32);
  }
  denp += __shfl_xor(denp, 8);
  denp += __shfl_xor(denp, 16);
  denp += __shfl_xor(denp, 32);
  float den = __shfl(denp, h) + selfw;
  float inv = 1.f/(den + 1e-16f);
  bf16x8 xv = *(const bf16x8*)(xr + (size_t)n*128 + c0);
  union { bf16x8 v; uint4 u; } xc; xc.v = xv;
  float xf[8] = { bflo(xc.u.x), bfhi(xc.u.x), bflo(xc.u.y), bfhi(xc.u.y),
                  bflo(xc.u.z), bfhi(xc.u.z), bflo(xc.u.w), bfhi(xc.u.w) };
  float4 bA = *(const float4*)(bias1f + c0), bB = *(const float4*)(bias1f + c0 + 4);
  float bb[8] = { bA.x,bA.y,bA.z,bA.w, bB.x,bB.y,bB.z,bB.w };
  float o[8];
  float s1 = 0.f, s2 = 0.f;
  #pragma unroll
  for (int j=0;j<8;++j){
    o[j] = acc[j]*inv + xf[j] + bb[j];
    s1 += o[j]; s2 += o[j]*o[j];
  }
  #pragma unroll
  for (int off=1; off<16; off<<=1){
    s1 += __shfl_xor(s1, off);
    s2 += __shfl_xor(s2, off);
  }
  float mu  = s1 * (1.f/128.f);
  float var = s2 * (1.f/128.f) - mu*mu;
  float rstd = rsqrtf(var + 1e-5f);
  float4 gA = *(const float4*)(gf + c0),   gB = *(const float4*)(gf + c0 + 4);
  float4 tA = *(const float4*)(bfta + c0), tB = *(const float4*)(bfta + c0 + 4);
  float gg[8] = { gA.x,gA.y,gA.z,gA.w, gB.x,gB.y,gB.z,gB.w };
  float tt[8] = { tA.x,tA.y,tA.z,tA.w, tB.x,tB.y,tB.z,tB.w };
  #pragma unroll
  for (int j=0;j<8;++j){
    float v = (o[j]-mu)*rstd*gg[j] + tt[j];
    o[j] = v > 0.f ? v : __expf(v) - 1.f;
  }
  if (g == 0){
    if (!f32){
      bf16x8 ov = packbf8((float4){o[0],o[1],o[2],o[3]}, (float4){o[4],o[5],o[6],o[7]});
      *(bf16x8*)((__hip_bfloat16*)dout + (size_t)n*128 + c0) = ov;
    } else {
      float* op = (float*)dout + (size_t)n*128 + c0;
      *(float4*)op     = (float4){o[0],o[1],o[2],o[3]};
      *(float4*)(op+4) = (float4){o[4],o[5],o[6],o[7]};
    }
  }
}

// ---- layer-2 aggregate; 1 wave/node.
__global__ __launch_bounds__(256) void agg2(const __hip_bfloat16* __restrict__ h2b,
    const float* __restrict__ as2, const float* __restrict__ ad2,
    const int* __restrict__ rowp, const int* __restrict__ csr,
    const float* __restrict__ bias2f,
    const int* __restrict__ flag, void* __restrict__ dout, int nn, int Etot){
  int f32 = *flag;
  int w = threadIdx.x >> 6, lane = threadIdx.x & 63;
  int n = blockIdx.x*4 + w;
  if (n >= nn) return;
  int g = lane >> 3, t = lane & 7;
  int c0 = t*8;
  float adst = ad2[n];
  float selfw = __expf(fminf(lrelu(as2[n] + adst), 30.f));
  float sw0 = (g == 0) ? selfw : 0.f;
  bf16x8 hs = *(const bf16x8*)(h2b + (size_t)n*64 + c0);
  float acc[8];
  { union { bf16x8 v; uint4 u; } cv; cv.v = hs;
    acc[0]=sw0*bflo(cv.u.x); acc[1]=sw0*bfhi(cv.u.x);
    acc[2]=sw0*bflo(cv.u.y); acc[3]=sw0*bfhi(cv.u.y);
    acc[4]=sw0*bflo(cv.u.z); acc[5]=sw0*bfhi(cv.u.z);
    acc[6]=sw0*bflo(cv.u.w); acc[7]=sw0*bfhi(cv.u.w); }
  float denp = 0.f;
  int p0 = rowp[n], pe = rowp[n+1];
  if (p0 < 0) p0 = 0; if (pe > Etot) pe = Etot;
  int p0u = __builtin_amdgcn_readfirstlane(p0);
  int peu = __builtin_amdgcn_readfirstlane(pe);
  for (int b = p0u; b < peu; b += 64){
    int ei = b + lane;
    int ji = ei < peu ? ei : peu-1;
    int si = csr[ji]; if ((unsigned)si >= (unsigned)nn) si = 0;
    float av = as2[si];
    float wv = __expf(fminf(lrelu(av + adst), 30.f)) * (ei < peu ? 1.f : 0.f);
    denp += wv;
    #pragma unroll
    for (int ib = 0; ib < 8; ib += 4){
      if (b + 8*ib < peu){
        bf16x8 hv[4]; float wb[4];
        #pragma unroll
        for (int u=0;u<4;++u){
          int i = ib + u;
          int sv = __shfl(si, g + 8*i);
          wb[u]  = __shfl(wv, g + 8*i);
          hv[u] = *(const bf16x8*)(h2b + (size_t)sv*64 + c0);
        }
        #pragma unroll
        for (int u=0;u<4;++u){
          union { bf16x8 v; uint4 uu; } cv; cv.v = hv[u];
          float wx = wb[u];
          acc[0] += wx*bflo(cv.uu.x); acc[1] += wx*bfhi(cv.uu.x);
          acc[2] += wx*bflo(cv.uu.y); acc[3] += wx*bfhi(cv.uu.y);
          acc[4] += wx*bflo(cv.uu.z); acc[5] += wx*bfhi(cv.uu.z);
          acc[6] += wx*bflo(cv.uu.w); acc[7] += wx*bfhi(cv.uu.w);
        }
      }
    }
  }
  #pragma unroll
  for (int j=0;j<8;++j){
    acc[j] += __shfl_xor(acc[j], 8);
    acc[j] += __shfl_xor(acc[j], 16);
    acc[j] += __shfl_xor(acc[j], 32);
  }
  denp += __shfl_xor(denp, 1);
  denp += __shfl_xor(denp, 2);
  denp += __shfl_xor(denp, 4);
  denp += __shfl_xor(denp, 8);
  denp += __shfl_xor(denp, 16);
  denp += __shfl_xor(denp, 32);
  float den = denp + selfw;
  float inv = 1.f/(den + 1e-16f);
  float4 bA = *(const float4*)(bias2f + c0), bB = *(const float4*)(bias2f + c0 + 4);
  float bb[8] = { bA.x,bA.y,bA.z,bA.w, bB.x,bB.y,bB.z,bB.w };
  float o[8];
  #pragma unroll
  for (int j=0;j<8;++j) o[j] = acc[j]*inv + bb[j];
  if (g == 0){
    if (!f32){
      bf16x8 ov = packbf8((float4){o[0],o[1],o[2],o[3]}, (float4){o[4],o[5],o[6],o[7]});
      *(bf16x8*)((__hip_bfloat16*)dout + (size_t)nn*128 + (size_t)n*64 + c0) = ov;
    } else {
      float* op = (float*)dout + (size_t)nn*128 + (size_t)n*64 + c0;
      *(float4*)op     = (float4){o[0],o[1],o[2],o[3]};
      *(float4*)(op+4) = (float4){o[4],o[5],o[6],o[7]};
    }
  }
}

extern "C" void kernel_launch(void* const* d_in, const int* in_sizes, int n_in,
                              void* d_out, int out_size, void* d_ws, size_t ws_size,
                              hipStream_t stream){
  (void)n_in; (void)out_size; (void)ws_size;
  const void* x     = d_in[0];
  const int*  ei    = (const int*)d_in[1];
  const void* W1    = d_in[2];
  const void* a1s   = d_in[3];
  const void* a1d   = d_in[4];
  const void* b1    = d_in[5];
  const void* resW  = d_in[6];
  const void* g     = d_in[7];
  const void* bt    = d_in[8];
  const void* W2    = d_in[9];
  const void* a2s   = d_in[10];
  const void* a2d   = d_in[11];
  const void* b2    = d_in[12];

  int N = in_sizes[0] / 128;
  int E = in_sizes[1] / 2;

  int s = 7;
  while ((((size_t)N + ((size_t)1 << s) - 1) >> s) > 1024) ++s;
  int NBK = (N + (1 << s) - 1) >> s;
  int M = NBK * 128;

  __hip_bfloat16* xrB = (__hip_bfloat16*)d_out;
  __hip_bfloat16* xrF = (__hip_bfloat16*)((float*)d_out + (size_t)N*128);

  char* ws = (char*)d_ws;
  size_t o = 0;
  auto alloc = [&](size_t bytes)->char*{ char* r = ws + o; o = (o + bytes + 255) & ~(size_t)255; return r; };
  int*   flag = (int*)  alloc(4);
  int*   part = (int*)  alloc(4096);
  int*   rowp = (int*)  alloc(((size_t)N+1)*4);
  float* as1  = (float*)alloc((size_t)N*8*4);
  float* ad1  = (float*)alloc((size_t)N*8*4);
  int*   csr  = (int*)  alloc((size_t)E*4);
  unsigned* bucketed = (unsigned*)alloc((size_t)E*4);
  int*   blockCounts = (int*)alloc((size_t)M*4);
  int*   scanned     = (int*)alloc((size_t)M*4);
  __hip_bfloat16* h1b = (__hip_bfloat16*)alloc((size_t)N*128*2);
  __hip_bfloat16* Bt1 = (__hip_bfloat16*)alloc(65536);
  __hip_bfloat16* W2t = (__hip_bfloat16*)alloc(16384);
  float* att1s  = (float*)alloc(512);
  float* att1d  = (float*)alloc(512);
  float* bias1f = (float*)alloc(512);
  float* gfv    = (float*)alloc(512);
  float* bfv    = (float*)alloc(512);
  float* att2s  = (float*)alloc(256);
  float* att2d  = (float*)alloc(256);
  float* bias2f = (float*)alloc(256);
  __hip_bfloat16* h2b = h1b;
  float* as2 = as1;
  float* ad2 = ad1;

  int G  = (N + 15)/16;
  int NBscan = (M + 1023)/1024;

  (void)hipMemsetAsync(flag, 0, 4, stream);
  detect<<<16, 256, 0, stream>>>((const unsigned short*)x, flag);
  prep<<<164, 256, 0, stream>>>(W1, resW, W2, a1s, a1d, b1, g, bt, a2s, a2d, b2,
                                Bt1, W2t, att1s, att1d, bias1f, gfv, bfv,
                                att2s, att2d, bias2f, flag);
  gemm1_fat<<<128 + G, 256, 0, stream>>>(x, Bt1, h1b, xrB, xrF,
                                         att1s, att1d, as1, ad1,
                                         ei, blockCounts, flag, N, E, G, s, NBK);
  scan_part<<<NBscan, 256, 0, stream>>>(blockCounts, part, M);
  scan_mid<<<1, 256, 0, stream>>>(part, NBscan, rowp, N);
  scan_write<<<NBscan, 256, 0, stream>>>(blockCounts, part, scanned, M);
  bucket_scatter<<<128, 256, 0, stream>>>(ei, scanned, bucketed, E, N, s, NBK);
  bucket_csr<<<NBK, 256, 0, stream>>>(bucketed, scanned, rowp, csr, N, s, NBK);
  agg1<<<(N+3)/4, 256, 0, stream>>>(h1b, as1, ad1, rowp, csr, xrB, xrF,
                                    bias1f, gfv, bfv, flag, d_out, N, E);
  gemm2_fat<<<G, 256, 0, stream>>>(d_out, W2t, h2b, att2s, att2d, as2, ad2, flag, N);
  agg2<<<(N+3)/4, 256, 0, stream>>>(h2b, as2, ad2, rowp, csr, bias2f, flag, d_out, N, E);
}